// Round 1
// baseline (889.500 us; speedup 1.0000x reference)
//
#include <hip/hip_runtime.h>
#include <hip/hip_bf16.h>
#include <cstdint>

// ---- problem constants ----
#define B_   2
#define L_   1024
#define H_   768
#define DI_  1536
#define DI2_ 3072      // 2*DI
#define DUP_ 12288     // 2*DI*4
#define DOUT_ 6144     // 4*DI
#define N_   16
#define R_   48
#define SPW  128       // padded ssm_p row stride (R + 2N = 80 -> 128)
#define BL_  2048      // B*L
#define C_   64        // scan chunks
#define CL_  16        // L_/C_ steps per chunk

typedef __bf16 bf16x8 __attribute__((ext_vector_type(8)));
typedef float  f32x4  __attribute__((ext_vector_type(4)));
typedef unsigned int u32;

__device__ __forceinline__ float silu_f(float v) {
    return v / (1.f + __expf(-v));
}

__device__ __forceinline__ void async_ld16(const void* g, void* lds) {
    __builtin_amdgcn_global_load_lds(
        (const __attribute__((address_space(1))) u32*)g,
        (__attribute__((address_space(3))) u32*)lds, 16, 0, 0);
}

// ---------------------------------------------------------------------------
// fp32 -> bf16 conversion, 8 elems/thread
// ---------------------------------------------------------------------------
__global__ void cvt_bf16(const float* __restrict__ src, __bf16* __restrict__ dst, int n)
{
    const int i = (blockIdx.x * blockDim.x + threadIdx.x) * 8;
    if (i < n) {
        const float4 a = *(const float4*)(src + i);
        const float4 b = *(const float4*)(src + i + 4);
        bf16x8 v;
        v[0] = (__bf16)a.x; v[1] = (__bf16)a.y; v[2] = (__bf16)a.z; v[3] = (__bf16)a.w;
        v[4] = (__bf16)b.x; v[5] = (__bf16)b.y; v[6] = (__bf16)b.z; v[7] = (__bf16)b.w;
        *(bf16x8*)(dst + i) = v;
    }
}

// x_proj_w [80][1536] fp32 -> [128][1536] bf16 with rows 80..127 zeroed
__global__ void pad_xp(const float* __restrict__ xp, __bf16* __restrict__ dst)
{
    const int i = (blockIdx.x * blockDim.x + threadIdx.x) * 8;   // < 128*1536
    const int j = i / DI_;
    bf16x8 v;
    if (j < 80) {
        const float4 a = *(const float4*)(xp + i);
        const float4 b = *(const float4*)(xp + i + 4);
        v[0] = (__bf16)a.x; v[1] = (__bf16)a.y; v[2] = (__bf16)a.z; v[3] = (__bf16)a.w;
        v[4] = (__bf16)b.x; v[5] = (__bf16)b.y; v[6] = (__bf16)b.z; v[7] = (__bf16)b.w;
    } else {
        for (int k = 0; k < 8; ++k) v[k] = (__bf16)0.f;
    }
    *(bf16x8*)(dst + i) = v;
}

// dt_w [1536][48] -> dtwT [48][1536] fp32
__global__ void transpose_dtw(const float* __restrict__ w, float* __restrict__ wT)
{
    const int i = blockIdx.x * blockDim.x + threadIdx.x;   // < 48*1536
    const int r = i / DI_, d = i % DI_;
    wT[i] = w[(size_t)d * R_ + r];
}

// ---------------------------------------------------------------------------
// bf16 MFMA GEMM (m97 structure + XOR bank swizzle), NT: Out = A * W^T
// 128x128 tile, BK=32, 256 threads. Kept for G1/G3/G5 (grid-granularity
// favors many small blocks at those shapes).
// ---------------------------------------------------------------------------
template<int EPI, int ATOMIC, typename OutT>
__global__ __launch_bounds__(256) void gemm_bf16(
    const __bf16* __restrict__ A, const __bf16* __restrict__ W, OutT* __restrict__ O,
    int M, int N, int Kslice, int lda, int ldw, int ldo)
{
    constexpr int BM = 128, BN = 128, BK = 32;
    __shared__ __bf16 As[BM * BK];
    __shared__ __bf16 Bs[BN * BK];

    const int tid  = threadIdx.x;
    const int bm   = blockIdx.x * BM;
    const int bn   = blockIdx.y * BN;
    const int kbase = blockIdx.z * Kslice;

    const int wave = tid >> 6, lane = tid & 63;
    const int wm = (wave >> 1) * 64, wn = (wave & 1) * 64;
    const int quad = lane >> 4, tr = lane & 15;

    const int srow = tid >> 2;
    const int skc  = ((tid & 3) ^ ((srow >> 1) & 3)) * 8;
    const __bf16* Ag0 = A + (size_t)(bm + srow) * lda + kbase + skc;
    const __bf16* Ag1 = A + (size_t)(bm + srow + 64) * lda + kbase + skc;
    const __bf16* Wg0 = W + (size_t)(bn + srow) * ldw + kbase + skc;
    const __bf16* Wg1 = W + (size_t)(bn + srow + 64) * ldw + kbase + skc;
    __bf16* Al0 = &As[tid * 8];
    __bf16* Al1 = &As[2048 + tid * 8];
    __bf16* Bl0 = &Bs[tid * 8];
    __bf16* Bl1 = &Bs[2048 + tid * 8];

    const int fsw = (quad ^ ((tr >> 1) & 3)) * 8;
    const __bf16* arp = &As[(wm + tr) * BK + fsw];
    const __bf16* brp = &Bs[(wn + tr) * BK + fsw];

    f32x4 acc[4][4];
#pragma unroll
    for (int i = 0; i < 4; ++i)
#pragma unroll
        for (int j = 0; j < 4; ++j) acc[i][j] = (f32x4){0.f, 0.f, 0.f, 0.f};

    for (int k0 = 0; k0 < Kslice; k0 += BK) {
        __syncthreads();
        async_ld16(Ag0 + k0, Al0);
        async_ld16(Ag1 + k0, Al1);
        async_ld16(Wg0 + k0, Bl0);
        async_ld16(Wg1 + k0, Bl1);
        __syncthreads();

        bf16x8 af[4], bfv[4];
#pragma unroll
        for (int i = 0; i < 4; ++i) af[i]  = *(const bf16x8*)(arp + i * 16 * BK);
#pragma unroll
        for (int j = 0; j < 4; ++j) bfv[j] = *(const bf16x8*)(brp + j * 16 * BK);
#pragma unroll
        for (int i = 0; i < 4; ++i)
#pragma unroll
            for (int j = 0; j < 4; ++j)
                acc[i][j] = __builtin_amdgcn_mfma_f32_16x16x32_bf16(af[i], bfv[j], acc[i][j], 0, 0, 0);
    }

#pragma unroll
    for (int i = 0; i < 4; ++i) {
        const int row = bm + wm + i * 16 + quad * 4;
#pragma unroll
        for (int j = 0; j < 4; ++j) {
            const int col = bn + wn + j * 16 + tr;
            OutT* op = O + (size_t)row * ldo + col;
#pragma unroll
            for (int r = 0; r < 4; ++r) {
                float v = acc[i][j][r];
                if (EPI == 1) v = silu_f(v);
                if (ATOMIC == 1) atomicAdd((float*)(op + (size_t)r * ldo), v);
                else             op[(size_t)r * ldo] = (OutT)v;
            }
        }
    }
}

// ---------------------------------------------------------------------------
// 256x256 8-wave deep-pipelined GEMM (T2+T3+T4+T5 per the regime-gate table).
// BK=32, 4-slot LDS ring (4 x (16KB A + 16KB B) = 128 KiB dynamic LDS).
// Staging runs 3 K-tiles ahead of compute; per-group gate is a counted
// s_waitcnt vmcnt(8) (= 2 tiles in flight) placed BEFORE the group barrier,
// so every wave's own global_load_lds for tile g+1 have landed before any
// wave reads them (cross-wave completion sealed by vmcnt+barrier).
// Slot (g+3)%4 is staged during group g; it was last read in group g-1
// (post-MFMA barrier of g-1 precedes the issue) -> no LDS write/read race.
// Raw s_barrier (NOT __syncthreads -> would re-insert the vmcnt(0) drain),
// sched_barrier(0) pins at phase boundaries, setprio(1) around each
// 16-MFMA cluster (T5 pays only in this phase-split structure).
// Chunk-XOR LDS swizzle identical to gemm_bf16 (bank-conflict-free, both
// sides permuted: pre-swizzled global source + swizzled fragment read).
// ---------------------------------------------------------------------------
template<int EPI, int ATOMIC, typename OutT>
__global__ __launch_bounds__(512, 2) void gemm256(
    const __bf16* __restrict__ A, const __bf16* __restrict__ W, OutT* __restrict__ O,
    int M, int N, int Kslice, int lda, int ldw, int ldo)
{
    extern __shared__ __bf16 S[];
    __bf16* AS = S;              // 4 slots * 8192 elems (256 rows x 32 k)
    __bf16* BS = S + 32768;      // 4 slots * 8192 elems

    const int tid = threadIdx.x;

    // bijective XCD-aware swizzle over the (x,y) tile grid (nxy % 8 == 0)
    const int nxy  = gridDim.x * gridDim.y;
    const int flat = blockIdx.x + gridDim.x * blockIdx.y;
    const int q    = nxy >> 3;
    const int swz  = (flat & 7) * q + (flat >> 3);
    const int bm   = (swz % gridDim.x) * 256;
    const int bn   = (swz / gridDim.x) * 256;
    const int kbase = blockIdx.z * Kslice;
    const int NT    = Kslice >> 5;          // K-tiles of 32

    // ---- staging addressing (512 thr x 16B = 8KB/round, 2 rounds/16KB piece)
    // thread t covers LDS row t>>2, chunk-slot t&3; slot c holds global
    // chunk c ^ ((row>>1)&3)  -> pre-swizzle the global source.
    const int srow = tid >> 2;                       // 0..127
    const int skc  = ((tid & 3) ^ ((tid >> 3) & 3)) * 8;
    const __bf16* Ag = A + (size_t)(bm + srow) * lda + kbase + skc;
    const __bf16* Wg = W + (size_t)(bn + srow) * ldw + kbase + skc;
    const size_t ldA128 = (size_t)128 * lda;
    const size_t ldW128 = (size_t)128 * ldw;
    __bf16* Asl = AS + tid * 8;                      // + slot*8192 (+4096 round1)
    __bf16* Bsl = BS + tid * 8;

    auto stageA = [&](int t) {
        const int sl = (t & 3) * 8192;
        const __bf16* g = Ag + t * 32;
        async_ld16(g,          Asl + sl);
        async_ld16(g + ldA128, Asl + sl + 4096);
    };
    auto stageB = [&](int t) {
        const int sl = (t & 3) * 8192;
        const __bf16* g = Wg + t * 32;
        async_ld16(g,          Bsl + sl);
        async_ld16(g + ldW128, Bsl + sl + 4096);
    };

    // ---- fragment addressing: 8 waves (2 M x 4 N), 128x64 out per wave
    const int wv = tid >> 6, lane = tid & 63;
    const int wr = wv >> 2, wc = wv & 3;
    const int quad = lane >> 4, tr = lane & 15;
    const int fsw = (quad ^ ((tr >> 1) & 3)) * 8;    // swizzled chunk read
    const __bf16* arp = AS + (wr * 128 + tr) * 32 + fsw;
    const __bf16* brp = BS + (wc * 64 + tr) * 32 + fsw;

    f32x4 acc[8][4];
#pragma unroll
    for (int i = 0; i < 8; ++i)
#pragma unroll
        for (int j = 0; j < 4; ++j) acc[i][j] = (f32x4){0.f, 0.f, 0.f, 0.f};

    // ---- prologue: prefetch tiles 0..2, gate tile 0 (tiles 1,2 in flight)
    const int npre = NT < 3 ? NT : 3;
    for (int t = 0; t < npre; ++t) { stageA(t); stageB(t); }
    __builtin_amdgcn_sched_barrier(0);
    if (NT > 3) asm volatile("s_waitcnt vmcnt(8)" ::: "memory");
    else        asm volatile("s_waitcnt vmcnt(0)" ::: "memory");
    __builtin_amdgcn_s_barrier();
    __builtin_amdgcn_sched_barrier(0);

    for (int g = 0; g < NT; ++g) {
        const int sl = (g & 3) * 8192;
        const __bf16* ar = arp + sl;
        const __bf16* br = brp + sl;
        bf16x8 a0[4], a1[4], bv[4];

        // ---------- phase 1: A[qr0] + B reads | stage A(g+3) | 16 MFMA ----
#pragma unroll
        for (int f = 0; f < 4; ++f) a0[f] = *(const bf16x8*)(ar + f * 16 * 32);
#pragma unroll
        for (int j = 0; j < 4; ++j) bv[j] = *(const bf16x8*)(br + j * 16 * 32);
        if (g + 3 < NT) stageA(g + 3);
        __builtin_amdgcn_sched_barrier(0);
        __builtin_amdgcn_s_barrier();
        __builtin_amdgcn_sched_barrier(0);
        __builtin_amdgcn_s_setprio(1);
#pragma unroll
        for (int f = 0; f < 4; ++f)
#pragma unroll
            for (int j = 0; j < 4; ++j)
                acc[f][j] = __builtin_amdgcn_mfma_f32_16x16x32_bf16(a0[f], bv[j], acc[f][j], 0, 0, 0);
        __builtin_amdgcn_s_setprio(0);
        __builtin_amdgcn_sched_barrier(0);
        __builtin_amdgcn_s_barrier();
        __builtin_amdgcn_sched_barrier(0);

        // ---------- phase 2: A[qr1] reads | stage B(g+3) | 16 MFMA | gate --
#pragma unroll
        for (int f = 0; f < 4; ++f) a1[f] = *(const bf16x8*)(ar + (64 + f * 16) * 32);
        if (g + 3 < NT) stageB(g + 3);
        __builtin_amdgcn_sched_barrier(0);
        __builtin_amdgcn_s_barrier();
        __builtin_amdgcn_sched_barrier(0);
        __builtin_amdgcn_s_setprio(1);
#pragma unroll
        for (int f = 0; f < 4; ++f)
#pragma unroll
            for (int j = 0; j < 4; ++j)
                acc[4 + f][j] = __builtin_amdgcn_mfma_f32_16x16x32_bf16(a1[f], bv[j], acc[4 + f][j], 0, 0, 0);
        __builtin_amdgcn_s_setprio(0);
        __builtin_amdgcn_sched_barrier(0);

        // gate for tile g+1: allow tiles g+2,g+3 (8 loads) to stay in flight
        const int rem = NT - 1 - g;
        if (rem >= 3)      asm volatile("s_waitcnt vmcnt(8)" ::: "memory");
        else if (rem == 2) asm volatile("s_waitcnt vmcnt(4)" ::: "memory");
        else if (rem == 1) asm volatile("s_waitcnt vmcnt(0)" ::: "memory");
        if (rem > 0) {
            __builtin_amdgcn_s_barrier();
            __builtin_amdgcn_sched_barrier(0);
        }
    }

    // ---- epilogue: D[row = quad*4 + r][col = tr] per 16x16 fragment
#pragma unroll
    for (int fi = 0; fi < 8; ++fi) {
        const int row = bm + wr * 128 + fi * 16 + quad * 4;
#pragma unroll
        for (int fj = 0; fj < 4; ++fj) {
            const int col = bn + wc * 64 + fj * 16 + tr;
            OutT* op = O + (size_t)row * ldo + col;
#pragma unroll
            for (int r = 0; r < 4; ++r) {
                float v = acc[fi][fj][r];
                if (EPI == 1) v = silu_f(v);
                if (ATOMIC == 1) atomicAdd((float*)(op + (size_t)r * ldo), v);
                else             op[(size_t)r * ldo] = (OutT)v;
            }
        }
    }
}

// ---------------------------------------------------------------------------
// depthwise causal conv (K=4) + bias + silu; writes fp32 HS and bf16 HSb
// ---------------------------------------------------------------------------
__global__ void conv_kernel(const float* __restrict__ P,
                            const float* __restrict__ cw, const float* __restrict__ cb,
                            float* __restrict__ HS, __bf16* __restrict__ HSb)
{
    const int t = blockIdx.x * blockDim.x + threadIdx.x;
    const int d = t % DI_;
    const int bl = t / DI_;
    const int l = bl % L_;
    const float4 w = *(const float4*)(cw + (size_t)d * 4);
    const float wk[4] = {w.x, w.y, w.z, w.w};
    float acc = cb[d];
#pragma unroll
    for (int k = 0; k < 4; ++k) {
        const int ls = l - 3 + k;
        if (ls >= 0)
            acc += wk[k] * P[(size_t)(bl - l + ls) * DI2_ + d];
    }
    const float h = silu_f(acc);
    HS[t]  = h;
    HSb[t] = (__bf16)h;
}

// ---------------------------------------------------------------------------
// dt[bl, d] = softplus(sum_r ts[bl, r] * dtwT[r, d] + dt_b[d])
// ---------------------------------------------------------------------------
__global__ void dt_kernel(const float* __restrict__ SP, const float* __restrict__ dtwT,
                          const float* __restrict__ dtb, float* __restrict__ DT)
{
    const int t = blockIdx.x * blockDim.x + threadIdx.x;
    const int d = t % DI_;
    const int bl = t / DI_;
    const float* ts = SP + (size_t)bl * SPW;
    float s = dtb[d];
#pragma unroll
    for (int r4 = 0; r4 < R_ / 4; ++r4) {
        const float4 tv = *(const float4*)(ts + r4 * 4);
        const float* wp = dtwT + (size_t)r4 * 4 * DI_ + d;
        s += tv.x * wp[0] + tv.y * wp[DI_] + tv.z * wp[2 * DI_] + tv.w * wp[3 * DI_];
    }
    DT[t] = (s > 20.f) ? s : log1pf(__expf(s));
}

// ---------------------------------------------------------------------------
// Chunked parallel scan, thread per (b,c,d), 16 n-states in registers.
// ---------------------------------------------------------------------------
__global__ __launch_bounds__(256) void scan_pass1(
    const float* __restrict__ DT, const float* __restrict__ HS,
    const float* __restrict__ SP, const float* __restrict__ A_log,
    float* __restrict__ Aprod, float* __restrict__ Bacc)
{
    const int t = blockIdx.x * blockDim.x + threadIdx.x;   // < B*C*DI
    const int d = t % DI_;
    const int y = t / DI_;
    const int c = y % C_;
    const int b = y / C_;
    float A[N_], s[N_], ap[N_];
    {
        const float4* alp = (const float4*)(A_log + (size_t)d * N_);
        const float4 a0 = alp[0], a1 = alp[1], a2 = alp[2], a3 = alp[3];
        const float av[N_] = {a0.x,a0.y,a0.z,a0.w, a1.x,a1.y,a1.z,a1.w,
                              a2.x,a2.y,a2.z,a2.w, a3.x,a3.y,a3.z,a3.w};
#pragma unroll
        for (int n = 0; n < N_; ++n) { A[n] = -__expf(av[n]); s[n] = 0.f; ap[n] = 1.f; }
    }
    for (int il = 0; il < CL_; ++il) {
        const size_t bl = (size_t)b * L_ + c * CL_ + il;
        const float dt = DT[bl * DI_ + d];
        const float hs = HS[bl * DI_ + d];
        const float4* Bp = (const float4*)(SP + bl * SPW + R_);
        const float4 b0 = Bp[0], b1 = Bp[1], b2 = Bp[2], b3 = Bp[3];
        const float Bv[N_] = {b0.x,b0.y,b0.z,b0.w, b1.x,b1.y,b1.z,b1.w,
                              b2.x,b2.y,b2.z,b2.w, b3.x,b3.y,b3.z,b3.w};
        const float dh = dt * hs;
#pragma unroll
        for (int n = 0; n < N_; ++n) {
            const float dA = __expf(dt * A[n]);
            s[n] = fmaf(dA, s[n], dh * Bv[n]);
            ap[n] *= dA;
        }
    }
    float4* Ap = (float4*)(Aprod + (size_t)t * N_);
    float4* Bc = (float4*)(Bacc  + (size_t)t * N_);
    Ap[0] = make_float4(ap[0], ap[1], ap[2], ap[3]);
    Ap[1] = make_float4(ap[4], ap[5], ap[6], ap[7]);
    Ap[2] = make_float4(ap[8], ap[9], ap[10], ap[11]);
    Ap[3] = make_float4(ap[12], ap[13], ap[14], ap[15]);
    Bc[0] = make_float4(s[0], s[1], s[2], s[3]);
    Bc[1] = make_float4(s[4], s[5], s[6], s[7]);
    Bc[2] = make_float4(s[8], s[9], s[10], s[11]);
    Bc[3] = make_float4(s[12], s[13], s[14], s[15]);
}

__global__ __launch_bounds__(256) void scan_pass2(
    const float* __restrict__ Aprod, const float* __restrict__ Bacc,
    float* __restrict__ Sinit)
{
    const int t = blockIdx.x * blockDim.x + threadIdx.x;    // < B*DI*N
    const int n = t & (N_ - 1);
    const int d = (t >> 4) % DI_;
    const int b = (t >> 4) / DI_;
    float s = 0.f;
    for (int c = 0; c < C_; ++c) {
        const size_t idx = (((size_t)b * C_ + c) * DI_ + d) * N_ + n;
        Sinit[idx] = s;
        s = fmaf(Aprod[idx], s, Bacc[idx]);
    }
}

__global__ __launch_bounds__(256) void scan_pass3(
    const float* __restrict__ DT, const float* __restrict__ HS,
    const float* __restrict__ SP, const float* __restrict__ P,
    const float* __restrict__ A_log, const float* __restrict__ Dv,
    const float* __restrict__ Sinit, __bf16* __restrict__ Y)
{
    const int t = blockIdx.x * blockDim.x + threadIdx.x;   // < B*C*DI
    const int d = t % DI_;
    const int y = t / DI_;
    const int c = y % C_;
    const int b = y / C_;
    float A[N_], s[N_];
    {
        const float4* alp = (const float4*)(A_log + (size_t)d * N_);
        const float4 a0 = alp[0], a1 = alp[1], a2 = alp[2], a3 = alp[3];
        const float av[N_] = {a0.x,a0.y,a0.z,a0.w, a1.x,a1.y,a1.z,a1.w,
                              a2.x,a2.y,a2.z,a2.w, a3.x,a3.y,a3.z,a3.w};
#pragma unroll
        for (int n = 0; n < N_; ++n) A[n] = -__expf(av[n]);
    }
    {
        const float4* sp = (const float4*)(Sinit + (size_t)t * N_);
        const float4 s0 = sp[0], s1 = sp[1], s2 = sp[2], s3 = sp[3];
        s[0]=s0.x; s[1]=s0.y; s[2]=s0.z; s[3]=s0.w;
        s[4]=s1.x; s[5]=s1.y; s[6]=s1.z; s[7]=s1.w;
        s[8]=s2.x; s[9]=s2.y; s[10]=s2.z; s[11]=s2.w;
        s[12]=s3.x; s[13]=s3.y; s[14]=s3.z; s[15]=s3.w;
    }
    const float Dd = Dv[d];
    for (int il = 0; il < CL_; ++il) {
        const size_t bl = (size_t)b * L_ + c * CL_ + il;
        const float dt = DT[bl * DI_ + d];
        const float hs = HS[bl * DI_ + d];
        const float4* Bp = (const float4*)(SP + bl * SPW + R_);
        const float4 b0 = Bp[0], b1 = Bp[1], b2 = Bp[2], b3 = Bp[3];
        const float4 c0 = Bp[4], c1 = Bp[5], c2 = Bp[6], c3 = Bp[7];
        const float Bv[N_] = {b0.x,b0.y,b0.z,b0.w, b1.x,b1.y,b1.z,b1.w,
                              b2.x,b2.y,b2.z,b2.w, b3.x,b3.y,b3.z,b3.w};
        const float Cv[N_] = {c0.x,c0.y,c0.z,c0.w, c1.x,c1.y,c1.z,c1.w,
                              c2.x,c2.y,c2.z,c2.w, c3.x,c3.y,c3.z,c3.w};
        const float dh = dt * hs;
        float acc = 0.f;
#pragma unroll
        for (int n = 0; n < N_; ++n) {
            const float dA = __expf(dt * A[n]);
            s[n] = fmaf(dA, s[n], dh * Bv[n]);
            acc = fmaf(s[n], Cv[n], acc);
        }
        const float g = P[bl * DI2_ + DI_ + d];
        Y[bl * DI_ + d] = (__bf16)((acc + hs * Dd) * silu_f(g));
    }
}

extern "C" void kernel_launch(void* const* d_in, const int* in_sizes, int n_in,
                              void* d_out, int out_size, void* d_ws, size_t ws_size,
                              hipStream_t stream) {
    const float* x        = (const float*)d_in[0];
    const float* w_up     = (const float*)d_in[1];
    const float* w_down   = (const float*)d_in[2];
    const float* conv_w   = (const float*)d_in[3];
    const float* conv_b   = (const float*)d_in[4];
    const float* x_proj_w = (const float*)d_in[5];
    const float* dt_w     = (const float*)d_in[6];
    const float* dt_b     = (const float*)d_in[7];
    const float* A_log    = (const float*)d_in[8];
    const float* Dvec     = (const float*)d_in[9];
    const float* w_oup    = (const float*)d_in[10];
    const float* w_odown  = (const float*)d_in[11];
    float* out = (float*)d_out;

    // one-time: allow 128 KiB dynamic LDS on the 256^2 kernels
    static bool attr_done = []() {
        hipFuncSetAttribute(reinterpret_cast<const void*>(&gemm256<0, 1, float>),
                            hipFuncAttributeMaxDynamicSharedMemorySize, 131072);
        hipFuncSetAttribute(reinterpret_cast<const void*>(&gemm256<1, 0, __bf16>),
                            hipFuncAttributeMaxDynamicSharedMemorySize, 131072);
        return true;
    }();
    (void)attr_done;

    // ---- workspace layout (unchanged) ----
    char* base = (char*)d_ws;
    __bf16* x_b      = (__bf16*)base;                      //  3,145,728
    __bf16* wup_b    = (__bf16*)(base + 3145728);          // 18,874,368
    float*  P        = (float*)base;                       // 25,165,824
    char* r2 = base + 25165824;
    __bf16* wdown_b  = (__bf16*)r2;                        // 75,497,472
    __bf16* HSb      = (__bf16*)r2;                        //  6,291,456
    float*  SPb      = (float*)(r2 + 6291456);             //  1,048,576
    float*  DTb      = (float*)(r2 + 7340032);             // 12,582,912
    __bf16* Yb       = (__bf16*)(r2 + 19922944);           //  6,291,456
    __bf16* XPpad    = (__bf16*)(r2 + 26214400);           //    393,216
    float*  dtwT     = (float*)(r2 + 26607616);            //    294,912
    __bf16* woup_b   = (__bf16*)(r2 + 26902528);           // 18,874,368
    __bf16* wodown_b = (__bf16*)(r2 + 45776896);           //  9,437,184
    char* r3 = r2 + 75497472;
    __bf16* U1b      = (__bf16*)r3;                        // 50,331,648
    __bf16* U2b      = (__bf16*)r3;                        // 25,165,824
    float*  Aprod    = (float*)r3;                         // 12,582,912
    float*  Bacc     = (float*)(r3 + 12582912);            // 12,582,912
    float*  Sinit    = (float*)(r3 + 25165824);            // 12,582,912
    char* r4 = r3 + 50331648;
    float*  HS       = (float*)r4;                         // 12,582,912

    // bf16 inputs for G1/G2
    cvt_bf16<<<(BL_ * H_) / 2048, 256, 0, stream>>>(x, x_b, BL_ * H_);
    cvt_bf16<<<(DUP_ * H_) / 2048, 256, 0, stream>>>(w_up, wup_b, DUP_ * H_);
    cvt_bf16<<<(DI2_ * DUP_) / 2048, 256, 0, stream>>>(w_down, wdown_b, DI2_ * DUP_);

    // G1: U1b = silu(x @ w_up^T)   [2048 x 12288], K=768  (old 128^2 kernel)
    gemm_bf16<1, 0, __bf16><<<dim3(16, 96, 1), 256, 0, stream>>>(
        x_b, wup_b, U1b, BL_, DUP_, H_, H_, H_, DUP_);

    // G2: P = U1 @ w_down^T  fp32 atomic, split-K x8   [2048 x 3072], K=12288
    // 256^2 deep-pipelined kernel: 768 blocks = 3 even rounds @ 1 block/CU
    hipMemsetAsync(P, 0, (size_t)BL_ * DI2_ * 4, stream);
    gemm256<0, 1, float><<<dim3(8, 12, 8), 512, 131072, stream>>>(
        U1b, wdown_b, P, BL_, DI2_, DUP_ / 8, DUP_, DUP_, DI2_);

    // wdown_b dead from here: build small operand copies in r2
    pad_xp<<<(128 * DI_) / 2048, 256, 0, stream>>>(x_proj_w, XPpad);
    transpose_dtw<<<(R_ * DI_) / 256, 256, 0, stream>>>(dt_w, dtwT);
    cvt_bf16<<<(DOUT_ * DI_) / 2048, 256, 0, stream>>>(w_oup, woup_b, DOUT_ * DI_);
    cvt_bf16<<<(H_ * DOUT_) / 2048, 256, 0, stream>>>(w_odown, wodown_b, H_ * DOUT_);

    // conv + silu -> HS fp32 + HSb bf16
    conv_kernel<<<(BL_ * DI_) / 256, 256, 0, stream>>>(P, conv_w, conv_b, HS, HSb);

    // ssm projection: SP[2048][128] = HSb @ XPpad^T, split-K x4 atomic
    hipMemsetAsync(SPb, 0, (size_t)BL_ * SPW * 4, stream);
    gemm_bf16<0, 1, float><<<dim3(16, 1, 4), 256, 0, stream>>>(
        HSb, XPpad, SPb, BL_, SPW, DI_ / 4, DI_, DI_, SPW);

    // dt -> DT
    dt_kernel<<<(BL_ * DI_) / 256, 256, 0, stream>>>(SPb, dtwT, dt_b, DTb);

    // chunked scan (C=64 chunks of 16)
    scan_pass1<<<(B_ * C_ * DI_) / 256, 256, 0, stream>>>(DTb, HS, SPb, A_log, Aprod, Bacc);
    scan_pass2<<<(B_ * DI_ * N_) / 256, 256, 0, stream>>>(Aprod, Bacc, Sinit);
    scan_pass3<<<(B_ * C_ * DI_) / 256, 256, 0, stream>>>(
        DTb, HS, SPb, P, A_log, Dvec, Sinit, Yb);

    // G4: U2b = silu(Y @ w_oup^T)   [2048 x 6144], K=1536  (256^2 kernel)
    gemm256<1, 0, __bf16><<<dim3(8, 24, 1), 512, 131072, stream>>>(
        Yb, woup_b, U2b, BL_, DOUT_, DI_, DI_, DI_, DOUT_);

    // G5: out = U2 @ w_odown^T  fp32 atomic, split-K x8   [2048 x 768], K=6144
    hipMemsetAsync(out, 0, (size_t)BL_ * H_ * 4, stream);
    gemm_bf16<0, 1, float><<<dim3(16, 6, 8), 256, 0, stream>>>(
        U2b, wodown_b, out, BL_, H_, DOUT_ / 8, DOUT_, DOUT_, H_);
}

// Round 2
// 871.702 us; speedup vs baseline: 1.0204x; 1.0204x over previous
//
#include <hip/hip_runtime.h>
#include <hip/hip_bf16.h>
#include <cstdint>

// ---- problem constants ----
#define B_   2
#define L_   1024
#define H_   768
#define DI_  1536
#define DI2_ 3072      // 2*DI
#define DUP_ 12288     // 2*DI*4
#define DOUT_ 6144     // 4*DI
#define N_   16
#define R_   48
#define SPW  128       // padded ssm_p row stride (R + 2N = 80 -> 128)
#define BL_  2048      // B*L
#define C_   64        // scan chunks
#define CL_  16        // L_/C_ steps per chunk

typedef __bf16 bf16x8 __attribute__((ext_vector_type(8)));
typedef float  f32x4  __attribute__((ext_vector_type(4)));
typedef unsigned int u32;

__device__ __forceinline__ float silu_f(float v) {
    return v / (1.f + __expf(-v));
}

__device__ __forceinline__ void async_ld16(const void* g, void* lds) {
    __builtin_amdgcn_global_load_lds(
        (const __attribute__((address_space(1))) u32*)g,
        (__attribute__((address_space(3))) u32*)lds, 16, 0, 0);
}

// ---------------------------------------------------------------------------
// fp32 -> bf16 conversion, 8 elems/thread
// ---------------------------------------------------------------------------
__global__ void cvt_bf16(const float* __restrict__ src, __bf16* __restrict__ dst, int n)
{
    const int i = (blockIdx.x * blockDim.x + threadIdx.x) * 8;
    if (i < n) {
        const float4 a = *(const float4*)(src + i);
        const float4 b = *(const float4*)(src + i + 4);
        bf16x8 v;
        v[0] = (__bf16)a.x; v[1] = (__bf16)a.y; v[2] = (__bf16)a.z; v[3] = (__bf16)a.w;
        v[4] = (__bf16)b.x; v[5] = (__bf16)b.y; v[6] = (__bf16)b.z; v[7] = (__bf16)b.w;
        *(bf16x8*)(dst + i) = v;
    }
}

// x_proj_w [80][1536] fp32 -> [128][1536] bf16 with rows 80..127 zeroed
__global__ void pad_xp(const float* __restrict__ xp, __bf16* __restrict__ dst)
{
    const int i = (blockIdx.x * blockDim.x + threadIdx.x) * 8;   // < 128*1536
    const int j = i / DI_;
    bf16x8 v;
    if (j < 80) {
        const float4 a = *(const float4*)(xp + i);
        const float4 b = *(const float4*)(xp + i + 4);
        v[0] = (__bf16)a.x; v[1] = (__bf16)a.y; v[2] = (__bf16)a.z; v[3] = (__bf16)a.w;
        v[4] = (__bf16)b.x; v[5] = (__bf16)b.y; v[6] = (__bf16)b.z; v[7] = (__bf16)b.w;
    } else {
        for (int k = 0; k < 8; ++k) v[k] = (__bf16)0.f;
    }
    *(bf16x8*)(dst + i) = v;
}

// dt_w [1536][48] -> dtwT [48][1536] fp32
__global__ void transpose_dtw(const float* __restrict__ w, float* __restrict__ wT)
{
    const int i = blockIdx.x * blockDim.x + threadIdx.x;   // < 48*1536
    const int r = i / DI_, d = i % DI_;
    wT[i] = w[(size_t)d * R_ + r];
}

// ---------------------------------------------------------------------------
// bf16 MFMA GEMM (m97 structure + XOR bank swizzle), NT: Out = A * W^T
// 128x128 tile, BK=32, 256 threads. Kept for G1/G3/G5.
// ---------------------------------------------------------------------------
template<int EPI, int ATOMIC, typename OutT>
__global__ __launch_bounds__(256) void gemm_bf16(
    const __bf16* __restrict__ A, const __bf16* __restrict__ W, OutT* __restrict__ O,
    int M, int N, int Kslice, int lda, int ldw, int ldo)
{
    constexpr int BM = 128, BN = 128, BK = 32;
    __shared__ __bf16 As[BM * BK];
    __shared__ __bf16 Bs[BN * BK];

    const int tid  = threadIdx.x;
    const int bm   = blockIdx.x * BM;
    const int bn   = blockIdx.y * BN;
    const int kbase = blockIdx.z * Kslice;

    const int wave = tid >> 6, lane = tid & 63;
    const int wm = (wave >> 1) * 64, wn = (wave & 1) * 64;
    const int quad = lane >> 4, tr = lane & 15;

    const int srow = tid >> 2;
    const int skc  = ((tid & 3) ^ ((srow >> 1) & 3)) * 8;
    const __bf16* Ag0 = A + (size_t)(bm + srow) * lda + kbase + skc;
    const __bf16* Ag1 = A + (size_t)(bm + srow + 64) * lda + kbase + skc;
    const __bf16* Wg0 = W + (size_t)(bn + srow) * ldw + kbase + skc;
    const __bf16* Wg1 = W + (size_t)(bn + srow + 64) * ldw + kbase + skc;
    __bf16* Al0 = &As[tid * 8];
    __bf16* Al1 = &As[2048 + tid * 8];
    __bf16* Bl0 = &Bs[tid * 8];
    __bf16* Bl1 = &Bs[2048 + tid * 8];

    const int fsw = (quad ^ ((tr >> 1) & 3)) * 8;
    const __bf16* arp = &As[(wm + tr) * BK + fsw];
    const __bf16* brp = &Bs[(wn + tr) * BK + fsw];

    f32x4 acc[4][4];
#pragma unroll
    for (int i = 0; i < 4; ++i)
#pragma unroll
        for (int j = 0; j < 4; ++j) acc[i][j] = (f32x4){0.f, 0.f, 0.f, 0.f};

    for (int k0 = 0; k0 < Kslice; k0 += BK) {
        __syncthreads();
        async_ld16(Ag0 + k0, Al0);
        async_ld16(Ag1 + k0, Al1);
        async_ld16(Wg0 + k0, Bl0);
        async_ld16(Wg1 + k0, Bl1);
        __syncthreads();

        bf16x8 af[4], bfv[4];
#pragma unroll
        for (int i = 0; i < 4; ++i) af[i]  = *(const bf16x8*)(arp + i * 16 * BK);
#pragma unroll
        for (int j = 0; j < 4; ++j) bfv[j] = *(const bf16x8*)(brp + j * 16 * BK);
#pragma unroll
        for (int i = 0; i < 4; ++i)
#pragma unroll
            for (int j = 0; j < 4; ++j)
                acc[i][j] = __builtin_amdgcn_mfma_f32_16x16x32_bf16(af[i], bfv[j], acc[i][j], 0, 0, 0);
    }

#pragma unroll
    for (int i = 0; i < 4; ++i) {
        const int row = bm + wm + i * 16 + quad * 4;
#pragma unroll
        for (int j = 0; j < 4; ++j) {
            const int col = bn + wn + j * 16 + tr;
            OutT* op = O + (size_t)row * ldo + col;
#pragma unroll
            for (int r = 0; r < 4; ++r) {
                float v = acc[i][j][r];
                if (EPI == 1) v = silu_f(v);
                if (ATOMIC == 1) atomicAdd((float*)(op + (size_t)r * ldo), v);
                else             op[(size_t)r * ldo] = (OutT)v;
            }
        }
    }
}

// ---------------------------------------------------------------------------
// 256x256 8-wave GEMM, BK=64, derived-waits pipeline (T2+T3+T4+T5).
// 2-slot LDS double buffer: per slot {A 256x64, B 256x64} = 64KB -> 128KB.
// Pieces per K-tile: 0=A-k0 1=B-k0 2=A-k1 3=B-k1 (16KB each, 2 loads/thr).
// Schedule per tile t (NO intra-tile drains, 2 barriers, 2 counted gates):
//   reads(A-k0,B-k0/n0)  stage(t+1,0)  16 MFMA
//   reads(B-k0/n1)       stage(t+1,1)  16 MFMA
//   vmcnt(4) barrier          <- seals A-k1(t),B-k1(t); allows t+1's k0 pair
//   reads(A-k1,B-k1/n0)  stage(t+1,2)  16 MFMA
//   reads(B-k1/n1)       stage(t+1,3)  16 MFMA
//   vmcnt(4) barrier          <- seals A-k0(t+1),B-k0(t+1)
// Hazards: every LDS region has >=1 barrier between last read (tile t-1)
// and next stage-issue (for tile t+1, same slot); every read sealed by a
// prior gate+barrier of all waves (vmcnt is per-wave; barrier makes it
// collective). In-flight = 2 pieces (4 loads) steady; drained only in tail.
// Chunk-XOR LDS swizzle identical to gemm_bf16 (both-sides permuted).
// ---------------------------------------------------------------------------
#define GATE_BAR(Nimm)                                          \
    asm volatile("s_waitcnt vmcnt(" #Nimm ")" ::: "memory");    \
    __builtin_amdgcn_sched_barrier(0);                          \
    __builtin_amdgcn_s_barrier();                               \
    __builtin_amdgcn_sched_barrier(0);

#define MFMA16(J0, J1, AF, B0, B1)                              \
    __builtin_amdgcn_s_setprio(1);                              \
    _Pragma("unroll")                                           \
    for (int f = 0; f < 8; ++f) {                               \
        acc[f][J0] = __builtin_amdgcn_mfma_f32_16x16x32_bf16(AF[f], B0, acc[f][J0], 0, 0, 0); \
        acc[f][J1] = __builtin_amdgcn_mfma_f32_16x16x32_bf16(AF[f], B1, acc[f][J1], 0, 0, 0); \
    }                                                           \
    __builtin_amdgcn_s_setprio(0);

template<int EPI, int ATOMIC, typename OutT>
__global__ __launch_bounds__(512, 2) void gemm256(
    const __bf16* __restrict__ A, const __bf16* __restrict__ W, OutT* __restrict__ O,
    int M, int N, int Kslice, int lda, int ldw, int ldo)
{
    extern __shared__ __bf16 S[];
    __bf16* AS = S;              // 2 slots * 16384 elems (2 k-halves * 256r * 32k)
    __bf16* BS = S + 32768;

    const int tid = threadIdx.x;

    // bijective XCD-aware swizzle over the (x,y) tile grid (nxy % 8 == 0)
    const int nxy  = gridDim.x * gridDim.y;
    const int flat = blockIdx.x + gridDim.x * blockIdx.y;
    const int q    = nxy >> 3;
    const int swz  = (flat & 7) * q + (flat >> 3);
    const int bm   = (swz % gridDim.x) * 256;
    const int bn   = (swz / gridDim.x) * 256;
    const int kbase = blockIdx.z * Kslice;
    const int NT    = Kslice >> 6;          // K-tiles of 64

    // ---- staging: thread t covers rows (t>>2, +128), chunk-slot t&3;
    // slot c holds global chunk c^((row>>1)&3) -> pre-swizzled source.
    const int srow = tid >> 2;
    const int skc  = ((tid & 3) ^ ((tid >> 3) & 3)) * 8;
    const __bf16* Ag = A + (size_t)(bm + srow) * lda + kbase + skc;
    const __bf16* Wg = W + (size_t)(bn + srow) * ldw + kbase + skc;
    const size_t ldA128 = (size_t)128 * lda;
    const size_t ldW128 = (size_t)128 * ldw;
    __bf16* Asl = AS + tid * 8;
    __bf16* Bsl = BS + tid * 8;

    // piece pc of tile t: pc: 0=A-k0 1=B-k0 2=A-k1 3=B-k1 (each 2 loads)
    auto stage = [&](int t, int pc) {
        const int off = (t & 1) * 16384 + (pc >> 1) * 8192;
        if (pc & 1) {
            const __bf16* g = Wg + t * 64 + (pc >> 1) * 32;
            async_ld16(g,          Bsl + off);
            async_ld16(g + ldW128, Bsl + off + 4096);
        } else {
            const __bf16* g = Ag + t * 64 + (pc >> 1) * 32;
            async_ld16(g,          Asl + off);
            async_ld16(g + ldA128, Asl + off + 4096);
        }
    };

    // ---- fragments: 8 waves (2M x 4N), 128x64 out per wave
    const int wv = tid >> 6, lane = tid & 63;
    const int wr = wv >> 2, wc = wv & 3;
    const int quad = lane >> 4, tr = lane & 15;
    const int fsw = (quad ^ ((tr >> 1) & 3)) * 8;
    // A frag (mf, kh): AS + slot + kh*8192 + wr*4096 + (mf*16+tr)*32 + fsw
    const __bf16* arp = AS + wr * 4096 + tr * 32 + fsw;
    // B frag (nh, g, kh): BS + slot + kh*8192 + (wc>>1)*4096
    //                        + ((wc&1)*64 + nh*32 + g*16 + tr)*32 + fsw
    const __bf16* brp = BS + (wc >> 1) * 4096 + ((wc & 1) * 64 + tr) * 32 + fsw;

    f32x4 acc[8][4];
#pragma unroll
    for (int i = 0; i < 8; ++i)
#pragma unroll
        for (int j = 0; j < 4; ++j) acc[i][j] = (f32x4){0.f, 0.f, 0.f, 0.f};

    // ---- prologue: all 4 pieces of tile 0; gate k0 pair (k1 pair in flight)
    stage(0, 0); stage(0, 1); stage(0, 2); stage(0, 3);
    GATE_BAR(4)

    for (int t = 0; t < NT - 1; ++t) {
        const int sl = (t & 1) * 16384;
        const __bf16* ar = arp + sl;
        const __bf16* br = brp + sl;
        bf16x8 af[8], b0, b1;
        // ---- k-half 0
#pragma unroll
        for (int f = 0; f < 8; ++f) af[f] = *(const bf16x8*)(ar + f * 512);
        b0 = *(const bf16x8*)(br);
        b1 = *(const bf16x8*)(br + 512);
        stage(t + 1, 0);
        MFMA16(0, 1, af, b0, b1)
        b0 = *(const bf16x8*)(br + 1024);
        b1 = *(const bf16x8*)(br + 1536);
        stage(t + 1, 1);
        MFMA16(2, 3, af, b0, b1)
        GATE_BAR(4)
        // ---- k-half 1
#pragma unroll
        for (int f = 0; f < 8; ++f) af[f] = *(const bf16x8*)(ar + 8192 + f * 512);
        b0 = *(const bf16x8*)(br + 8192);
        b1 = *(const bf16x8*)(br + 8192 + 512);
        stage(t + 1, 2);
        MFMA16(0, 1, af, b0, b1)
        b0 = *(const bf16x8*)(br + 8192 + 1024);
        b1 = *(const bf16x8*)(br + 8192 + 1536);
        stage(t + 1, 3);
        MFMA16(2, 3, af, b0, b1)
        GATE_BAR(4)
    }
    {   // ---- tail tile NT-1: no staging; drain k1 pair mid-tile
        const int sl = ((NT - 1) & 1) * 16384;
        const __bf16* ar = arp + sl;
        const __bf16* br = brp + sl;
        bf16x8 af[8], b0, b1;
#pragma unroll
        for (int f = 0; f < 8; ++f) af[f] = *(const bf16x8*)(ar + f * 512);
        b0 = *(const bf16x8*)(br);
        b1 = *(const bf16x8*)(br + 512);
        MFMA16(0, 1, af, b0, b1)
        b0 = *(const bf16x8*)(br + 1024);
        b1 = *(const bf16x8*)(br + 1536);
        MFMA16(2, 3, af, b0, b1)
        GATE_BAR(0)
#pragma unroll
        for (int f = 0; f < 8; ++f) af[f] = *(const bf16x8*)(ar + 8192 + f * 512);
        b0 = *(const bf16x8*)(br + 8192);
        b1 = *(const bf16x8*)(br + 8192 + 512);
        MFMA16(0, 1, af, b0, b1)
        b0 = *(const bf16x8*)(br + 8192 + 1024);
        b1 = *(const bf16x8*)(br + 8192 + 1536);
        MFMA16(2, 3, af, b0, b1)
    }

    // ---- epilogue: D[row = quad*4 + r][col = tr] per 16x16 fragment
#pragma unroll
    for (int fi = 0; fi < 8; ++fi) {
        const int row = bm + wr * 128 + fi * 16 + quad * 4;
#pragma unroll
        for (int fj = 0; fj < 4; ++fj) {
            const int col = bn + wc * 64 + fj * 16 + tr;
            OutT* op = O + (size_t)row * ldo + col;
#pragma unroll
            for (int r = 0; r < 4; ++r) {
                float v = acc[fi][fj][r];
                if (EPI == 1) v = silu_f(v);
                if (ATOMIC == 1) atomicAdd((float*)(op + (size_t)r * ldo), v);
                else             op[(size_t)r * ldo] = (OutT)v;
            }
        }
    }
}

// ---------------------------------------------------------------------------
// depthwise causal conv (K=4) + bias + silu; writes fp32 HS and bf16 HSb
// ---------------------------------------------------------------------------
__global__ void conv_kernel(const float* __restrict__ P,
                            const float* __restrict__ cw, const float* __restrict__ cb,
                            float* __restrict__ HS, __bf16* __restrict__ HSb)
{
    const int t = blockIdx.x * blockDim.x + threadIdx.x;
    const int d = t % DI_;
    const int bl = t / DI_;
    const int l = bl % L_;
    const float4 w = *(const float4*)(cw + (size_t)d * 4);
    const float wk[4] = {w.x, w.y, w.z, w.w};
    float acc = cb[d];
#pragma unroll
    for (int k = 0; k < 4; ++k) {
        const int ls = l - 3 + k;
        if (ls >= 0)
            acc += wk[k] * P[(size_t)(bl - l + ls) * DI2_ + d];
    }
    const float h = silu_f(acc);
    HS[t]  = h;
    HSb[t] = (__bf16)h;
}

// ---------------------------------------------------------------------------
// dt[bl, d] = softplus(sum_r ts[bl, r] * dtwT[r, d] + dt_b[d])
// ---------------------------------------------------------------------------
__global__ void dt_kernel(const float* __restrict__ SP, const float* __restrict__ dtwT,
                          const float* __restrict__ dtb, float* __restrict__ DT)
{
    const int t = blockIdx.x * blockDim.x + threadIdx.x;
    const int d = t % DI_;
    const int bl = t / DI_;
    const float* ts = SP + (size_t)bl * SPW;
    float s = dtb[d];
#pragma unroll
    for (int r4 = 0; r4 < R_ / 4; ++r4) {
        const float4 tv = *(const float4*)(ts + r4 * 4);
        const float* wp = dtwT + (size_t)r4 * 4 * DI_ + d;
        s += tv.x * wp[0] + tv.y * wp[DI_] + tv.z * wp[2 * DI_] + tv.w * wp[3 * DI_];
    }
    DT[t] = (s > 20.f) ? s : log1pf(__expf(s));
}

// ---------------------------------------------------------------------------
// Chunked parallel scan, thread per (b,c,d), 16 n-states in registers.
// ---------------------------------------------------------------------------
__global__ __launch_bounds__(256) void scan_pass1(
    const float* __restrict__ DT, const float* __restrict__ HS,
    const float* __restrict__ SP, const float* __restrict__ A_log,
    float* __restrict__ Aprod, float* __restrict__ Bacc)
{
    const int t = blockIdx.x * blockDim.x + threadIdx.x;   // < B*C*DI
    const int d = t % DI_;
    const int y = t / DI_;
    const int c = y % C_;
    const int b = y / C_;
    float A[N_], s[N_], ap[N_];
    {
        const float4* alp = (const float4*)(A_log + (size_t)d * N_);
        const float4 a0 = alp[0], a1 = alp[1], a2 = alp[2], a3 = alp[3];
        const float av[N_] = {a0.x,a0.y,a0.z,a0.w, a1.x,a1.y,a1.z,a1.w,
                              a2.x,a2.y,a2.z,a2.w, a3.x,a3.y,a3.z,a3.w};
#pragma unroll
        for (int n = 0; n < N_; ++n) { A[n] = -__expf(av[n]); s[n] = 0.f; ap[n] = 1.f; }
    }
    for (int il = 0; il < CL_; ++il) {
        const size_t bl = (size_t)b * L_ + c * CL_ + il;
        const float dt = DT[bl * DI_ + d];
        const float hs = HS[bl * DI_ + d];
        const float4* Bp = (const float4*)(SP + bl * SPW + R_);
        const float4 b0 = Bp[0], b1 = Bp[1], b2 = Bp[2], b3 = Bp[3];
        const float Bv[N_] = {b0.x,b0.y,b0.z,b0.w, b1.x,b1.y,b1.z,b1.w,
                              b2.x,b2.y,b2.z,b2.w, b3.x,b3.y,b3.z,b3.w};
        const float dh = dt * hs;
#pragma unroll
        for (int n = 0; n < N_; ++n) {
            const float dA = __expf(dt * A[n]);
            s[n] = fmaf(dA, s[n], dh * Bv[n]);
            ap[n] *= dA;
        }
    }
    float4* Ap = (float4*)(Aprod + (size_t)t * N_);
    float4* Bc = (float4*)(Bacc  + (size_t)t * N_);
    Ap[0] = make_float4(ap[0], ap[1], ap[2], ap[3]);
    Ap[1] = make_float4(ap[4], ap[5], ap[6], ap[7]);
    Ap[2] = make_float4(ap[8], ap[9], ap[10], ap[11]);
    Ap[3] = make_float4(ap[12], ap[13], ap[14], ap[15]);
    Bc[0] = make_float4(s[0], s[1], s[2], s[3]);
    Bc[1] = make_float4(s[4], s[5], s[6], s[7]);
    Bc[2] = make_float4(s[8], s[9], s[10], s[11]);
    Bc[3] = make_float4(s[12], s[13], s[14], s[15]);
}

__global__ __launch_bounds__(256) void scan_pass2(
    const float* __restrict__ Aprod, const float* __restrict__ Bacc,
    float* __restrict__ Sinit)
{
    const int t = blockIdx.x * blockDim.x + threadIdx.x;    // < B*DI*N
    const int n = t & (N_ - 1);
    const int d = (t >> 4) % DI_;
    const int b = (t >> 4) / DI_;
    float s = 0.f;
    for (int c = 0; c < C_; ++c) {
        const size_t idx = (((size_t)b * C_ + c) * DI_ + d) * N_ + n;
        Sinit[idx] = s;
        s = fmaf(Aprod[idx], s, Bacc[idx]);
    }
}

__global__ __launch_bounds__(256) void scan_pass3(
    const float* __restrict__ DT, const float* __restrict__ HS,
    const float* __restrict__ SP, const float* __restrict__ P,
    const float* __restrict__ A_log, const float* __restrict__ Dv,
    const float* __restrict__ Sinit, __bf16* __restrict__ Y)
{
    const int t = blockIdx.x * blockDim.x + threadIdx.x;   // < B*C*DI
    const int d = t % DI_;
    const int y = t / DI_;
    const int c = y % C_;
    const int b = y / C_;
    float A[N_], s[N_];
    {
        const float4* alp = (const float4*)(A_log + (size_t)d * N_);
        const float4 a0 = alp[0], a1 = alp[1], a2 = alp[2], a3 = alp[3];
        const float av[N_] = {a0.x,a0.y,a0.z,a0.w, a1.x,a1.y,a1.z,a1.w,
                              a2.x,a2.y,a2.z,a2.w, a3.x,a3.y,a3.z,a3.w};
#pragma unroll
        for (int n = 0; n < N_; ++n) A[n] = -__expf(av[n]);
    }
    {
        const float4* sp = (const float4*)(Sinit + (size_t)t * N_);
        const float4 s0 = sp[0], s1 = sp[1], s2 = sp[2], s3 = sp[3];
        s[0]=s0.x; s[1]=s0.y; s[2]=s0.z; s[3]=s0.w;
        s[4]=s1.x; s[5]=s1.y; s[6]=s1.z; s[7]=s1.w;
        s[8]=s2.x; s[9]=s2.y; s[10]=s2.z; s[11]=s2.w;
        s[12]=s3.x; s[13]=s3.y; s[14]=s3.z; s[15]=s3.w;
    }
    const float Dd = Dv[d];
    for (int il = 0; il < CL_; ++il) {
        const size_t bl = (size_t)b * L_ + c * CL_ + il;
        const float dt = DT[bl * DI_ + d];
        const float hs = HS[bl * DI_ + d];
        const float4* Bp = (const float4*)(SP + bl * SPW + R_);
        const float4 b0 = Bp[0], b1 = Bp[1], b2 = Bp[2], b3 = Bp[3];
        const float4 c0 = Bp[4], c1 = Bp[5], c2 = Bp[6], c3 = Bp[7];
        const float Bv[N_] = {b0.x,b0.y,b0.z,b0.w, b1.x,b1.y,b1.z,b1.w,
                              b2.x,b2.y,b2.z,b2.w, b3.x,b3.y,b3.z,b3.w};
        const float Cv[N_] = {c0.x,c0.y,c0.z,c0.w, c1.x,c1.y,c1.z,c1.w,
                              c2.x,c2.y,c2.z,c2.w, c3.x,c3.y,c3.z,c3.w};
        const float dh = dt * hs;
        float acc = 0.f;
#pragma unroll
        for (int n = 0; n < N_; ++n) {
            const float dA = __expf(dt * A[n]);
            s[n] = fmaf(dA, s[n], dh * Bv[n]);
            acc = fmaf(s[n], Cv[n], acc);
        }
        const float g = P[bl * DI2_ + DI_ + d];
        Y[bl * DI_ + d] = (__bf16)((acc + hs * Dd) * silu_f(g));
    }
}

extern "C" void kernel_launch(void* const* d_in, const int* in_sizes, int n_in,
                              void* d_out, int out_size, void* d_ws, size_t ws_size,
                              hipStream_t stream) {
    const float* x        = (const float*)d_in[0];
    const float* w_up     = (const float*)d_in[1];
    const float* w_down   = (const float*)d_in[2];
    const float* conv_w   = (const float*)d_in[3];
    const float* conv_b   = (const float*)d_in[4];
    const float* x_proj_w = (const float*)d_in[5];
    const float* dt_w     = (const float*)d_in[6];
    const float* dt_b     = (const float*)d_in[7];
    const float* A_log    = (const float*)d_in[8];
    const float* Dvec     = (const float*)d_in[9];
    const float* w_oup    = (const float*)d_in[10];
    const float* w_odown  = (const float*)d_in[11];
    float* out = (float*)d_out;

    // one-time: allow 128 KiB dynamic LDS on the 256^2 kernels
    static bool attr_done = []() {
        hipFuncSetAttribute(reinterpret_cast<const void*>(&gemm256<0, 1, float>),
                            hipFuncAttributeMaxDynamicSharedMemorySize, 131072);
        hipFuncSetAttribute(reinterpret_cast<const void*>(&gemm256<1, 0, __bf16>),
                            hipFuncAttributeMaxDynamicSharedMemorySize, 131072);
        return true;
    }();
    (void)attr_done;

    // ---- workspace layout (unchanged) ----
    char* base = (char*)d_ws;
    __bf16* x_b      = (__bf16*)base;                      //  3,145,728
    __bf16* wup_b    = (__bf16*)(base + 3145728);          // 18,874,368
    float*  P        = (float*)base;                       // 25,165,824
    char* r2 = base + 25165824;
    __bf16* wdown_b  = (__bf16*)r2;                        // 75,497,472
    __bf16* HSb      = (__bf16*)r2;                        //  6,291,456
    float*  SPb      = (float*)(r2 + 6291456);             //  1,048,576
    float*  DTb      = (float*)(r2 + 7340032);             // 12,582,912
    __bf16* Yb       = (__bf16*)(r2 + 19922944);           //  6,291,456
    __bf16* XPpad    = (__bf16*)(r2 + 26214400);           //    393,216
    float*  dtwT     = (float*)(r2 + 26607616);            //    294,912
    __bf16* woup_b   = (__bf16*)(r2 + 26902528);           // 18,874,368
    __bf16* wodown_b = (__bf16*)(r2 + 45776896);           //  9,437,184
    char* r3 = r2 + 75497472;
    __bf16* U1b      = (__bf16*)r3;                        // 50,331,648
    __bf16* U2b      = (__bf16*)r3;                        // 25,165,824
    float*  Aprod    = (float*)r3;                         // 12,582,912
    float*  Bacc     = (float*)(r3 + 12582912);            // 12,582,912
    float*  Sinit    = (float*)(r3 + 25165824);            // 12,582,912
    char* r4 = r3 + 50331648;
    float*  HS       = (float*)r4;                         // 12,582,912

    // bf16 inputs for G1/G2
    cvt_bf16<<<(BL_ * H_) / 2048, 256, 0, stream>>>(x, x_b, BL_ * H_);
    cvt_bf16<<<(DUP_ * H_) / 2048, 256, 0, stream>>>(w_up, wup_b, DUP_ * H_);
    cvt_bf16<<<(DI2_ * DUP_) / 2048, 256, 0, stream>>>(w_down, wdown_b, DI2_ * DUP_);

    // G1: U1b = silu(x @ w_up^T)   [2048 x 12288], K=768  (old 128^2 kernel)
    gemm_bf16<1, 0, __bf16><<<dim3(16, 96, 1), 256, 0, stream>>>(
        x_b, wup_b, U1b, BL_, DUP_, H_, H_, H_, DUP_);

    // G2: P = U1 @ w_down^T  fp32 atomic, split-K x8   [2048 x 3072], K=12288
    // derived-waits 256^2 kernel: 768 blocks = 3 even rounds @ 1 block/CU
    hipMemsetAsync(P, 0, (size_t)BL_ * DI2_ * 4, stream);
    gemm256<0, 1, float><<<dim3(8, 12, 8), 512, 131072, stream>>>(
        U1b, wdown_b, P, BL_, DI2_, DUP_ / 8, DUP_, DUP_, DI2_);

    // wdown_b dead from here: build small operand copies in r2
    pad_xp<<<(128 * DI_) / 2048, 256, 0, stream>>>(x_proj_w, XPpad);
    transpose_dtw<<<(R_ * DI_) / 256, 256, 0, stream>>>(dt_w, dtwT);
    cvt_bf16<<<(DOUT_ * DI_) / 2048, 256, 0, stream>>>(w_oup, woup_b, DOUT_ * DI_);
    cvt_bf16<<<(H_ * DOUT_) / 2048, 256, 0, stream>>>(w_odown, wodown_b, H_ * DOUT_);

    // conv + silu -> HS fp32 + HSb bf16
    conv_kernel<<<(BL_ * DI_) / 256, 256, 0, stream>>>(P, conv_w, conv_b, HS, HSb);

    // ssm projection: SP[2048][128] = HSb @ XPpad^T, split-K x4 atomic
    hipMemsetAsync(SPb, 0, (size_t)BL_ * SPW * 4, stream);
    gemm_bf16<0, 1, float><<<dim3(16, 1, 4), 256, 0, stream>>>(
        HSb, XPpad, SPb, BL_, SPW, DI_ / 4, DI_, DI_, SPW);

    // dt -> DT
    dt_kernel<<<(BL_ * DI_) / 256, 256, 0, stream>>>(SPb, dtwT, dt_b, DTb);

    // chunked scan (C=64 chunks of 16)
    scan_pass1<<<(B_ * C_ * DI_) / 256, 256, 0, stream>>>(DTb, HS, SPb, A_log, Aprod, Bacc);
    scan_pass2<<<(B_ * DI_ * N_) / 256, 256, 0, stream>>>(Aprod, Bacc, Sinit);
    scan_pass3<<<(B_ * C_ * DI_) / 256, 256, 0, stream>>>(
        DTb, HS, SPb, P, A_log, Dvec, Sinit, Yb);

    // G4: U2b = silu(Y @ w_oup^T)   [2048 x 6144], K=1536  (256^2 kernel)
    gemm256<1, 0, __bf16><<<dim3(8, 24, 1), 512, 131072, stream>>>(
        Yb, woup_b, U2b, BL_, DOUT_, DI_, DI_, DI_, DOUT_);

    // G5: out = U2 @ w_odown^T  fp32 atomic, split-K x8   [2048 x 768], K=6144
    hipMemsetAsync(out, 0, (size_t)BL_ * H_ * 4, stream);
    gemm_bf16<0, 1, float><<<dim3(16, 6, 8), 256, 0, stream>>>(
        U2b, wodown_b, out, BL_, H_, DOUT_ / 8, DOUT_, DOUT_, H_);
}

// Round 3
// 825.236 us; speedup vs baseline: 1.0779x; 1.0563x over previous
//
#include <hip/hip_runtime.h>
#include <hip/hip_bf16.h>
#include <cstdint>

// ---- problem constants ----
#define B_   2
#define L_   1024
#define H_   768
#define DI_  1536
#define DI2_ 3072      // 2*DI
#define DUP_ 12288     // 2*DI*4
#define DOUT_ 6144     // 4*DI
#define N_   16
#define R_   48
#define SPW  128       // padded ssm_p row stride (R + 2N = 80 -> 128)
#define BL_  2048      // B*L
#define C_   64        // scan chunks
#define CL_  16        // L_/C_ steps per chunk

typedef __bf16 bf16x8 __attribute__((ext_vector_type(8)));
typedef float  f32x4  __attribute__((ext_vector_type(4)));
typedef unsigned int u32;

__device__ __forceinline__ float silu_f(float v) {
    return v / (1.f + __expf(-v));
}

__device__ __forceinline__ void async_ld16(const void* g, void* lds) {
    __builtin_amdgcn_global_load_lds(
        (const __attribute__((address_space(1))) u32*)g,
        (__attribute__((address_space(3))) u32*)lds, 16, 0, 0);
}

__device__ __forceinline__ void cvt8(const float* __restrict__ s, __bf16* __restrict__ d, int i)
{
    const float4 a = *(const float4*)(s + i);
    const float4 b = *(const float4*)(s + i + 4);
    bf16x8 v;
    v[0] = (__bf16)a.x; v[1] = (__bf16)a.y; v[2] = (__bf16)a.z; v[3] = (__bf16)a.w;
    v[4] = (__bf16)b.x; v[5] = (__bf16)b.y; v[6] = (__bf16)b.z; v[7] = (__bf16)b.w;
    *(bf16x8*)(d + i) = v;
}

// ---------------------------------------------------------------------------
// prep1: fused fp32->bf16 conversions needed before G1/G2.
// segs: x (768 blk), w_up (4608), w_down (18432); 256 thr x 8 elems each.
// ---------------------------------------------------------------------------
__global__ void prep1(const float* __restrict__ x, const float* __restrict__ wup,
                      const float* __restrict__ wdn,
                      __bf16* __restrict__ xb, __bf16* __restrict__ wupb,
                      __bf16* __restrict__ wdnb)
{
    const int bid = blockIdx.x;
    if (bid < 768)            cvt8(x,   xb,   (bid * 256 + threadIdx.x) * 8);
    else if (bid < 5376)      cvt8(wup, wupb, ((bid - 768) * 256 + threadIdx.x) * 8);
    else                      cvt8(wdn, wdnb, ((bid - 5376) * 256 + threadIdx.x) * 8);
}

// ---------------------------------------------------------------------------
// prep2: fused prep after G2 (overlays dead wdown_b region).
// segs: w_oup (4608), w_odown (2304), pad_xp (96), transpose_dtw (288).
// ---------------------------------------------------------------------------
__global__ void prep2(const float* __restrict__ woup, const float* __restrict__ wodn,
                      const float* __restrict__ xp, const float* __restrict__ dtw,
                      __bf16* __restrict__ woupb, __bf16* __restrict__ wodnb,
                      __bf16* __restrict__ xppad, float* __restrict__ dtwT)
{
    const int bid = blockIdx.x;
    if (bid < 4608)        cvt8(woup, woupb, (bid * 256 + threadIdx.x) * 8);
    else if (bid < 6912)   cvt8(wodn, wodnb, ((bid - 4608) * 256 + threadIdx.x) * 8);
    else if (bid < 7008) {
        const int i = ((bid - 6912) * 256 + threadIdx.x) * 8;   // < 128*1536
        const int j = i / DI_;
        bf16x8 v;
        if (j < 80) {
            const float4 a = *(const float4*)(xp + i);
            const float4 b = *(const float4*)(xp + i + 4);
            v[0] = (__bf16)a.x; v[1] = (__bf16)a.y; v[2] = (__bf16)a.z; v[3] = (__bf16)a.w;
            v[4] = (__bf16)b.x; v[5] = (__bf16)b.y; v[6] = (__bf16)b.z; v[7] = (__bf16)b.w;
        } else {
            for (int k = 0; k < 8; ++k) v[k] = (__bf16)0.f;
        }
        *(bf16x8*)(xppad + i) = v;
    } else {
        const int i = (bid - 7008) * 256 + threadIdx.x;         // < 48*1536
        const int r = i / DI_, d = i % DI_;
        dtwT[i] = dtw[(size_t)d * R_ + r];
    }
}

// ---------------------------------------------------------------------------
// bf16 MFMA GEMM (m97 structure + XOR bank swizzle), NT: Out = A * W^T
// 128x128 tile, BK=32, 256 threads, global_load_lds width-16 staging.
// ATOMIC=0 + gridDim.z>1: plain-store split-K, partial z at O + z*M*ldo.
// ---------------------------------------------------------------------------
template<int EPI, int ATOMIC, typename OutT>
__global__ __launch_bounds__(256) void gemm_bf16(
    const __bf16* __restrict__ A, const __bf16* __restrict__ W, OutT* __restrict__ O,
    int M, int N, int Kslice, int lda, int ldw, int ldo)
{
    constexpr int BM = 128, BN = 128, BK = 32;
    __shared__ __bf16 As[BM * BK];
    __shared__ __bf16 Bs[BN * BK];

    const int tid  = threadIdx.x;
    const int bm   = blockIdx.x * BM;
    const int bn   = blockIdx.y * BN;
    const int kbase = blockIdx.z * Kslice;
    if (ATOMIC == 0) O += (size_t)blockIdx.z * (size_t)M * ldo;  // partial buffer

    const int wave = tid >> 6, lane = tid & 63;
    const int wm = (wave >> 1) * 64, wn = (wave & 1) * 64;
    const int quad = lane >> 4, tr = lane & 15;

    // staging: thread (srow, c) stores global k-chunk c^((srow>>1)&3) into slot c
    const int srow = tid >> 2;
    const int skc  = ((tid & 3) ^ ((srow >> 1) & 3)) * 8;
    const __bf16* Ag0 = A + (size_t)(bm + srow) * lda + kbase + skc;
    const __bf16* Ag1 = A + (size_t)(bm + srow + 64) * lda + kbase + skc;
    const __bf16* Wg0 = W + (size_t)(bn + srow) * ldw + kbase + skc;
    const __bf16* Wg1 = W + (size_t)(bn + srow + 64) * ldw + kbase + skc;
    __bf16* Al0 = &As[tid * 8];
    __bf16* Al1 = &As[2048 + tid * 8];
    __bf16* Bl0 = &Bs[tid * 8];
    __bf16* Bl1 = &Bs[2048 + tid * 8];

    // fragment read: row (wm|wn)+tr, want global chunk `quad` -> slot quad^((tr>>1)&3)
    const int fsw = (quad ^ ((tr >> 1) & 3)) * 8;
    const __bf16* arp = &As[(wm + tr) * BK + fsw];
    const __bf16* brp = &Bs[(wn + tr) * BK + fsw];

    f32x4 acc[4][4];
#pragma unroll
    for (int i = 0; i < 4; ++i)
#pragma unroll
        for (int j = 0; j < 4; ++j) acc[i][j] = (f32x4){0.f, 0.f, 0.f, 0.f};

    for (int k0 = 0; k0 < Kslice; k0 += BK) {
        __syncthreads();
        async_ld16(Ag0 + k0, Al0);
        async_ld16(Ag1 + k0, Al1);
        async_ld16(Wg0 + k0, Bl0);
        async_ld16(Wg1 + k0, Bl1);
        __syncthreads();

        bf16x8 af[4], bfv[4];
#pragma unroll
        for (int i = 0; i < 4; ++i) af[i]  = *(const bf16x8*)(arp + i * 16 * BK);
#pragma unroll
        for (int j = 0; j < 4; ++j) bfv[j] = *(const bf16x8*)(brp + j * 16 * BK);
#pragma unroll
        for (int i = 0; i < 4; ++i)
#pragma unroll
            for (int j = 0; j < 4; ++j)
                acc[i][j] = __builtin_amdgcn_mfma_f32_16x16x32_bf16(af[i], bfv[j], acc[i][j], 0, 0, 0);
    }

    // epilogue: D[row=quad*4+r][col=lane&15] (m89/m91 layout)
#pragma unroll
    for (int i = 0; i < 4; ++i) {
        const int row = bm + wm + i * 16 + quad * 4;
#pragma unroll
        for (int j = 0; j < 4; ++j) {
            const int col = bn + wn + j * 16 + tr;
            OutT* op = O + (size_t)row * ldo + col;
#pragma unroll
            for (int r = 0; r < 4; ++r) {
                float v = acc[i][j][r];
                if (EPI == 1) v = silu_f(v);
                if (ATOMIC == 1) atomicAdd((float*)(op + (size_t)r * ldo), v);
                else             op[(size_t)r * ldo] = (OutT)v;
            }
        }
    }
}

// ---------------------------------------------------------------------------
// depthwise causal conv (K=4) + bias + silu over P0+P1 (split-K partials);
// writes fp32 HS and bf16 HSb
// ---------------------------------------------------------------------------
__global__ void conv_kernel(const float* __restrict__ P0, const float* __restrict__ P1,
                            const float* __restrict__ cw, const float* __restrict__ cb,
                            float* __restrict__ HS, __bf16* __restrict__ HSb)
{
    const int t = blockIdx.x * blockDim.x + threadIdx.x;
    const int d = t % DI_;
    const int bl = t / DI_;
    const int l = bl % L_;
    const float4 w = *(const float4*)(cw + (size_t)d * 4);
    const float wk[4] = {w.x, w.y, w.z, w.w};
    float acc = cb[d];
#pragma unroll
    for (int k = 0; k < 4; ++k) {
        const int ls = l - 3 + k;
        if (ls >= 0) {
            const size_t idx = (size_t)(bl - l + ls) * DI2_ + d;
            acc += wk[k] * (P0[idx] + P1[idx]);
        }
    }
    const float h = silu_f(acc);
    HS[t]  = h;
    HSb[t] = (__bf16)h;
}

// ---------------------------------------------------------------------------
// dt[bl, d] = softplus(sum_r ts[bl, r] * dtwT[r, d] + dt_b[d])
// ---------------------------------------------------------------------------
__global__ void dt_kernel(const float* __restrict__ SP, const float* __restrict__ dtwT,
                          const float* __restrict__ dtb, float* __restrict__ DT)
{
    const int t = blockIdx.x * blockDim.x + threadIdx.x;
    const int d = t % DI_;
    const int bl = t / DI_;
    const float* ts = SP + (size_t)bl * SPW;
    float s = dtb[d];
#pragma unroll
    for (int r4 = 0; r4 < R_ / 4; ++r4) {
        const float4 tv = *(const float4*)(ts + r4 * 4);
        const float* wp = dtwT + (size_t)r4 * 4 * DI_ + d;
        s += tv.x * wp[0] + tv.y * wp[DI_] + tv.z * wp[2 * DI_] + tv.w * wp[3 * DI_];
    }
    DT[t] = (s > 20.f) ? s : log1pf(__expf(s));
}

// ---------------------------------------------------------------------------
// Chunked parallel scan, thread per (b,c,d), 16 n-states in registers.
// ---------------------------------------------------------------------------
__global__ __launch_bounds__(256) void scan_pass1(
    const float* __restrict__ DT, const float* __restrict__ HS,
    const float* __restrict__ SP, const float* __restrict__ A_log,
    float* __restrict__ Aprod, float* __restrict__ Bacc)
{
    const int t = blockIdx.x * blockDim.x + threadIdx.x;   // < B*C*DI
    const int d = t % DI_;
    const int y = t / DI_;
    const int c = y % C_;
    const int b = y / C_;
    float A[N_], s[N_], ap[N_];
    {
        const float4* alp = (const float4*)(A_log + (size_t)d * N_);
        const float4 a0 = alp[0], a1 = alp[1], a2 = alp[2], a3 = alp[3];
        const float av[N_] = {a0.x,a0.y,a0.z,a0.w, a1.x,a1.y,a1.z,a1.w,
                              a2.x,a2.y,a2.z,a2.w, a3.x,a3.y,a3.z,a3.w};
#pragma unroll
        for (int n = 0; n < N_; ++n) { A[n] = -__expf(av[n]); s[n] = 0.f; ap[n] = 1.f; }
    }
    for (int il = 0; il < CL_; ++il) {
        const size_t bl = (size_t)b * L_ + c * CL_ + il;
        const float dt = DT[bl * DI_ + d];
        const float hs = HS[bl * DI_ + d];
        const float4* Bp = (const float4*)(SP + bl * SPW + R_);
        const float4 b0 = Bp[0], b1 = Bp[1], b2 = Bp[2], b3 = Bp[3];
        const float Bv[N_] = {b0.x,b0.y,b0.z,b0.w, b1.x,b1.y,b1.z,b1.w,
                              b2.x,b2.y,b2.z,b2.w, b3.x,b3.y,b3.z,b3.w};
        const float dh = dt * hs;
#pragma unroll
        for (int n = 0; n < N_; ++n) {
            const float dA = __expf(dt * A[n]);
            s[n] = fmaf(dA, s[n], dh * Bv[n]);
            ap[n] *= dA;
        }
    }
    float4* Ap = (float4*)(Aprod + (size_t)t * N_);
    float4* Bc = (float4*)(Bacc  + (size_t)t * N_);
    Ap[0] = make_float4(ap[0], ap[1], ap[2], ap[3]);
    Ap[1] = make_float4(ap[4], ap[5], ap[6], ap[7]);
    Ap[2] = make_float4(ap[8], ap[9], ap[10], ap[11]);
    Ap[3] = make_float4(ap[12], ap[13], ap[14], ap[15]);
    Bc[0] = make_float4(s[0], s[1], s[2], s[3]);
    Bc[1] = make_float4(s[4], s[5], s[6], s[7]);
    Bc[2] = make_float4(s[8], s[9], s[10], s[11]);
    Bc[3] = make_float4(s[12], s[13], s[14], s[15]);
}

__global__ __launch_bounds__(256) void scan_pass2(
    const float* __restrict__ Aprod, const float* __restrict__ Bacc,
    float* __restrict__ Sinit)
{
    const int t = blockIdx.x * blockDim.x + threadIdx.x;    // < B*DI*N
    const int n = t & (N_ - 1);
    const int d = (t >> 4) % DI_;
    const int b = (t >> 4) / DI_;
    float s = 0.f;
    for (int c = 0; c < C_; ++c) {
        const size_t idx = (((size_t)b * C_ + c) * DI_ + d) * N_ + n;
        Sinit[idx] = s;
        s = fmaf(Aprod[idx], s, Bacc[idx]);
    }
}

__global__ __launch_bounds__(256) void scan_pass3(
    const float* __restrict__ DT, const float* __restrict__ HS,
    const float* __restrict__ SP, const float* __restrict__ P0,
    const float* __restrict__ P1, const float* __restrict__ A_log,
    const float* __restrict__ Dv, const float* __restrict__ Sinit,
    __bf16* __restrict__ Y)
{
    const int t = blockIdx.x * blockDim.x + threadIdx.x;   // < B*C*DI
    const int d = t % DI_;
    const int y = t / DI_;
    const int c = y % C_;
    const int b = y / C_;
    float A[N_], s[N_];
    {
        const float4* alp = (const float4*)(A_log + (size_t)d * N_);
        const float4 a0 = alp[0], a1 = alp[1], a2 = alp[2], a3 = alp[3];
        const float av[N_] = {a0.x,a0.y,a0.z,a0.w, a1.x,a1.y,a1.z,a1.w,
                              a2.x,a2.y,a2.z,a2.w, a3.x,a3.y,a3.z,a3.w};
#pragma unroll
        for (int n = 0; n < N_; ++n) A[n] = -__expf(av[n]);
    }
    {
        const float4* sp = (const float4*)(Sinit + (size_t)t * N_);
        const float4 s0 = sp[0], s1 = sp[1], s2 = sp[2], s3 = sp[3];
        s[0]=s0.x; s[1]=s0.y; s[2]=s0.z; s[3]=s0.w;
        s[4]=s1.x; s[5]=s1.y; s[6]=s1.z; s[7]=s1.w;
        s[8]=s2.x; s[9]=s2.y; s[10]=s2.z; s[11]=s2.w;
        s[12]=s3.x; s[13]=s3.y; s[14]=s3.z; s[15]=s3.w;
    }
    const float Dd = Dv[d];
    for (int il = 0; il < CL_; ++il) {
        const size_t bl = (size_t)b * L_ + c * CL_ + il;
        const float dt = DT[bl * DI_ + d];
        const float hs = HS[bl * DI_ + d];
        const float4* Bp = (const float4*)(SP + bl * SPW + R_);
        const float4 b0 = Bp[0], b1 = Bp[1], b2 = Bp[2], b3 = Bp[3];
        const float4 c0 = Bp[4], c1 = Bp[5], c2 = Bp[6], c3 = Bp[7];
        const float Bv[N_] = {b0.x,b0.y,b0.z,b0.w, b1.x,b1.y,b1.z,b1.w,
                              b2.x,b2.y,b2.z,b2.w, b3.x,b3.y,b3.z,b3.w};
        const float Cv[N_] = {c0.x,c0.y,c0.z,c0.w, c1.x,c1.y,c1.z,c1.w,
                              c2.x,c2.y,c2.z,c2.w, c3.x,c3.y,c3.z,c3.w};
        const float dh = dt * hs;
        float acc = 0.f;
#pragma unroll
        for (int n = 0; n < N_; ++n) {
            const float dA = __expf(dt * A[n]);
            s[n] = fmaf(dA, s[n], dh * Bv[n]);
            acc = fmaf(s[n], Cv[n], acc);
        }
        const size_t gidx = bl * DI2_ + DI_ + d;
        const float g = P0[gidx] + P1[gidx];
        Y[bl * DI_ + d] = (__bf16)((acc + hs * Dd) * silu_f(g));
    }
}

extern "C" void kernel_launch(void* const* d_in, const int* in_sizes, int n_in,
                              void* d_out, int out_size, void* d_ws, size_t ws_size,
                              hipStream_t stream) {
    const float* x        = (const float*)d_in[0];
    const float* w_up     = (const float*)d_in[1];
    const float* w_down   = (const float*)d_in[2];
    const float* conv_w   = (const float*)d_in[3];
    const float* conv_b   = (const float*)d_in[4];
    const float* x_proj_w = (const float*)d_in[5];
    const float* dt_w     = (const float*)d_in[6];
    const float* dt_b     = (const float*)d_in[7];
    const float* A_log    = (const float*)d_in[8];
    const float* Dvec     = (const float*)d_in[9];
    const float* w_oup    = (const float*)d_in[10];
    const float* w_odown  = (const float*)d_in[11];
    float* out = (float*)d_out;

    // ---- workspace layout, peak 176.2 MB (183+ proven safe) ----
    // phase A (prep1,G1): x_b[0,3.1) wup_b[3.1,22.0) wdown_b[50.3,125.8) U1b[125.8,176.2)
    // phase B (G2):       P0[0,25.2) P1[25.2,50.3) + wdown_b + U1b
    // phase C (post-G2):  wdown region -> {HSb,SPb,DTb,Yb,XPpad,dtwT,woup_b,wodown_b}
    //                     U1b region   -> {Aprod,Bacc,Sinit,HS}; U2b over Aprod+Bacc after pass3
    char* base = (char*)d_ws;
    __bf16* x_b      = (__bf16*)base;                      //  3,145,728
    __bf16* wup_b    = (__bf16*)(base + 3145728);          // 18,874,368
    float*  P0       = (float*)base;                       // 25,165,824
    float*  P1       = (float*)(base + 25165824);          // 25,165,824
    char* r2 = base + 50331648;
    __bf16* wdown_b  = (__bf16*)r2;                        // 75,497,472
    __bf16* HSb      = (__bf16*)r2;                        //  6,291,456
    float*  SPb      = (float*)(r2 + 6291456);             //  1,048,576
    float*  DTb      = (float*)(r2 + 7340032);             // 12,582,912
    __bf16* Yb       = (__bf16*)(r2 + 19922944);           //  6,291,456
    __bf16* XPpad    = (__bf16*)(r2 + 26214400);           //    393,216
    float*  dtwT     = (float*)(r2 + 26607616);            //    294,912
    __bf16* woup_b   = (__bf16*)(r2 + 26902528);           // 18,874,368
    __bf16* wodown_b = (__bf16*)(r2 + 45776896);           //  9,437,184
    char* r3 = r2 + 75497472;
    __bf16* U1b      = (__bf16*)r3;                        // 50,331,648
    __bf16* U2b      = (__bf16*)r3;                        // 25,165,824 (after pass3)
    float*  Aprod    = (float*)r3;                         // 12,582,912
    float*  Bacc     = (float*)(r3 + 12582912);            // 12,582,912
    float*  Sinit    = (float*)(r3 + 25165824);            // 12,582,912
    float*  HS       = (float*)(r3 + 37748736);            // 12,582,912

    // fused prep: x, w_up, w_down -> bf16
    prep1<<<23808, 256, 0, stream>>>(x, w_up, w_down, x_b, wup_b, wdown_b);

    // G1: U1b = silu(x @ w_up^T)   [2048 x 12288], K=768
    gemm_bf16<1, 0, __bf16><<<dim3(16, 96, 1), 256, 0, stream>>>(
        x_b, wup_b, U1b, BL_, DUP_, H_, H_, H_, DUP_);

    // G2: P = U1 @ w_down^T  [2048 x 3072], K=12288, split-K x2 into plain-
    // store partials P0,P1 (no memset, no atomics; summed at consumers)
    gemm_bf16<0, 0, float><<<dim3(16, 24, 2), 256, 0, stream>>>(
        U1b, wdown_b, P0, BL_, DI2_, DUP_ / 2, DUP_, DUP_, DI2_);

    // wdown_b dead from here: fused prep of small operands into r2
    prep2<<<7296, 256, 0, stream>>>(w_oup, w_odown, x_proj_w, dt_w,
                                    woup_b, wodown_b, XPpad, dtwT);

    // conv + silu over P0+P1 -> HS fp32 + HSb bf16
    conv_kernel<<<(BL_ * DI_) / 256, 256, 0, stream>>>(P0, P1, conv_w, conv_b, HS, HSb);

    // ssm projection: SP[2048][128] = HSb @ XPpad^T, split-K x4 atomic
    hipMemsetAsync(SPb, 0, (size_t)BL_ * SPW * 4, stream);
    gemm_bf16<0, 1, float><<<dim3(16, 1, 4), 256, 0, stream>>>(
        HSb, XPpad, SPb, BL_, SPW, DI_ / 4, DI_, DI_, SPW);

    // dt -> DT
    dt_kernel<<<(BL_ * DI_) / 256, 256, 0, stream>>>(SPb, dtwT, dt_b, DTb);

    // chunked scan (C=64 chunks of 16)
    scan_pass1<<<(B_ * C_ * DI_) / 256, 256, 0, stream>>>(DTb, HS, SPb, A_log, Aprod, Bacc);
    scan_pass2<<<(B_ * DI_ * N_) / 256, 256, 0, stream>>>(Aprod, Bacc, Sinit);
    scan_pass3<<<(B_ * C_ * DI_) / 256, 256, 0, stream>>>(
        DTb, HS, SPb, P0, P1, A_log, Dvec, Sinit, Yb);

    // G4: U2b = silu(Y @ w_oup^T)   [2048 x 6144], K=1536
    gemm_bf16<1, 0, __bf16><<<dim3(16, 48, 1), 256, 0, stream>>>(
        Yb, woup_b, U2b, BL_, DOUT_, DI_, DI_, DI_, DOUT_);

    // G5: out = U2 @ w_odown^T  fp32 atomic, split-K x8   [2048 x 768], K=6144
    hipMemsetAsync(out, 0, (size_t)BL_ * H_ * 4, stream);
    gemm_bf16<0, 1, float><<<dim3(16, 6, 8), 256, 0, stream>>>(
        U2b, wodown_b, out, BL_, H_, DOUT_ / 8, DOUT_, DOUT_, H_);
}

// Round 4
// 820.865 us; speedup vs baseline: 1.0836x; 1.0053x over previous
//
#include <hip/hip_runtime.h>
#include <hip/hip_bf16.h>
#include <cstdint>

// ---- problem constants ----
#define B_   2
#define L_   1024
#define H_   768
#define DI_  1536
#define DI2_ 3072      // 2*DI
#define DUP_ 12288     // 2*DI*4
#define DOUT_ 6144     // 4*DI
#define N_   16
#define R_   48
#define SPW  128       // padded ssm_p row stride (R + 2N = 80 -> 128)
#define BL_  2048      // B*L
#define C_   64        // scan chunks
#define CL_  16        // L_/C_ steps per chunk

typedef __bf16 bf16x8 __attribute__((ext_vector_type(8)));
typedef float  f32x4  __attribute__((ext_vector_type(4)));
typedef unsigned int u32;

__device__ __forceinline__ float silu_f(float v) {
    return v / (1.f + __expf(-v));
}

__device__ __forceinline__ void async_ld16(const void* g, void* lds) {
    __builtin_amdgcn_global_load_lds(
        (const __attribute__((address_space(1))) u32*)g,
        (__attribute__((address_space(3))) u32*)lds, 16, 0, 0);
}

__device__ __forceinline__ void cvt8(const float* __restrict__ s, __bf16* __restrict__ d, int i)
{
    const float4 a = *(const float4*)(s + i);
    const float4 b = *(const float4*)(s + i + 4);
    bf16x8 v;
    v[0] = (__bf16)a.x; v[1] = (__bf16)a.y; v[2] = (__bf16)a.z; v[3] = (__bf16)a.w;
    v[4] = (__bf16)b.x; v[5] = (__bf16)b.y; v[6] = (__bf16)b.z; v[7] = (__bf16)b.w;
    *(bf16x8*)(d + i) = v;
}

// ---------------------------------------------------------------------------
// prep1: fused fp32->bf16 conversions needed before G1/G2.
// segs: x (768 blk), w_up (4608), w_down (18432); 256 thr x 8 elems each.
// ---------------------------------------------------------------------------
__global__ void prep1(const float* __restrict__ x, const float* __restrict__ wup,
                      const float* __restrict__ wdn,
                      __bf16* __restrict__ xb, __bf16* __restrict__ wupb,
                      __bf16* __restrict__ wdnb)
{
    const int bid = blockIdx.x;
    if (bid < 768)            cvt8(x,   xb,   (bid * 256 + threadIdx.x) * 8);
    else if (bid < 5376)      cvt8(wup, wupb, ((bid - 768) * 256 + threadIdx.x) * 8);
    else                      cvt8(wdn, wdnb, ((bid - 5376) * 256 + threadIdx.x) * 8);
}

// ---------------------------------------------------------------------------
// prep2: fused prep after G2 (overlays dead wdown_b region).
// segs: w_oup (4608), w_odown (2304), pad_xp (96), transpose_dtw (288).
// ---------------------------------------------------------------------------
__global__ void prep2(const float* __restrict__ woup, const float* __restrict__ wodn,
                      const float* __restrict__ xp, const float* __restrict__ dtw,
                      __bf16* __restrict__ woupb, __bf16* __restrict__ wodnb,
                      __bf16* __restrict__ xppad, float* __restrict__ dtwT)
{
    const int bid = blockIdx.x;
    if (bid < 4608)        cvt8(woup, woupb, (bid * 256 + threadIdx.x) * 8);
    else if (bid < 6912)   cvt8(wodn, wodnb, ((bid - 4608) * 256 + threadIdx.x) * 8);
    else if (bid < 7008) {
        const int i = ((bid - 6912) * 256 + threadIdx.x) * 8;   // < 128*1536
        const int j = i / DI_;
        bf16x8 v;
        if (j < 80) {
            const float4 a = *(const float4*)(xp + i);
            const float4 b = *(const float4*)(xp + i + 4);
            v[0] = (__bf16)a.x; v[1] = (__bf16)a.y; v[2] = (__bf16)a.z; v[3] = (__bf16)a.w;
            v[4] = (__bf16)b.x; v[5] = (__bf16)b.y; v[6] = (__bf16)b.z; v[7] = (__bf16)b.w;
        } else {
            for (int k = 0; k < 8; ++k) v[k] = (__bf16)0.f;
        }
        *(bf16x8*)(xppad + i) = v;
    } else {
        const int i = (bid - 7008) * 256 + threadIdx.x;         // < 48*1536
        const int r = i / DI_, d = i % DI_;
        dtwT[i] = dtw[(size_t)d * R_ + r];
    }
}

// ---------------------------------------------------------------------------
// bf16 MFMA GEMM (m97 structure + XOR bank swizzle), NT: Out = A * W^T
// 128x128 tile, BK=32, 256 threads, global_load_lds width-16 staging.
// ATOMIC=0 + gridDim.z>1: plain-store split-K, partial z at O + z*M*ldo.
// SWZ=1: bijective XCD-chunked tile swizzle over (x,y) grid (needs nxy%8==0)
// so each XCD owns a contiguous tile run -> B-panel L2 reuse.
// ---------------------------------------------------------------------------
template<int EPI, int ATOMIC, int SWZ, typename OutT>
__global__ __launch_bounds__(256) void gemm_bf16(
    const __bf16* __restrict__ A, const __bf16* __restrict__ W, OutT* __restrict__ O,
    int M, int N, int Kslice, int lda, int ldw, int ldo)
{
    constexpr int BM = 128, BN = 128, BK = 32;
    __shared__ __bf16 As[BM * BK];
    __shared__ __bf16 Bs[BN * BK];

    const int tid  = threadIdx.x;
    int bx = blockIdx.x, by = blockIdx.y;
    if (SWZ) {
        const int nxy  = gridDim.x * gridDim.y;     // must be % 8 == 0
        const int flat = blockIdx.x + gridDim.x * blockIdx.y;
        const int qq   = nxy >> 3;
        const int s    = (flat & 7) * qq + (flat >> 3);
        bx = s % gridDim.x; by = s / gridDim.x;
    }
    const int bm   = bx * BM;
    const int bn   = by * BN;
    const int kbase = blockIdx.z * Kslice;
    if (ATOMIC == 0) O += (size_t)blockIdx.z * (size_t)M * ldo;  // partial buffer

    const int wave = tid >> 6, lane = tid & 63;
    const int wm = (wave >> 1) * 64, wn = (wave & 1) * 64;
    const int quad = lane >> 4, tr = lane & 15;

    // staging: thread (srow, c) stores global k-chunk c^((srow>>1)&3) into slot c
    const int srow = tid >> 2;
    const int skc  = ((tid & 3) ^ ((srow >> 1) & 3)) * 8;
    const __bf16* Ag0 = A + (size_t)(bm + srow) * lda + kbase + skc;
    const __bf16* Ag1 = A + (size_t)(bm + srow + 64) * lda + kbase + skc;
    const __bf16* Wg0 = W + (size_t)(bn + srow) * ldw + kbase + skc;
    const __bf16* Wg1 = W + (size_t)(bn + srow + 64) * ldw + kbase + skc;
    __bf16* Al0 = &As[tid * 8];
    __bf16* Al1 = &As[2048 + tid * 8];
    __bf16* Bl0 = &Bs[tid * 8];
    __bf16* Bl1 = &Bs[2048 + tid * 8];

    // fragment read: row (wm|wn)+tr, want global chunk `quad` -> slot quad^((tr>>1)&3)
    const int fsw = (quad ^ ((tr >> 1) & 3)) * 8;
    const __bf16* arp = &As[(wm + tr) * BK + fsw];
    const __bf16* brp = &Bs[(wn + tr) * BK + fsw];

    f32x4 acc[4][4];
#pragma unroll
    for (int i = 0; i < 4; ++i)
#pragma unroll
        for (int j = 0; j < 4; ++j) acc[i][j] = (f32x4){0.f, 0.f, 0.f, 0.f};

    for (int k0 = 0; k0 < Kslice; k0 += BK) {
        __syncthreads();
        async_ld16(Ag0 + k0, Al0);
        async_ld16(Ag1 + k0, Al1);
        async_ld16(Wg0 + k0, Bl0);
        async_ld16(Wg1 + k0, Bl1);
        __syncthreads();

        bf16x8 af[4], bfv[4];
#pragma unroll
        for (int i = 0; i < 4; ++i) af[i]  = *(const bf16x8*)(arp + i * 16 * BK);
#pragma unroll
        for (int j = 0; j < 4; ++j) bfv[j] = *(const bf16x8*)(brp + j * 16 * BK);
#pragma unroll
        for (int i = 0; i < 4; ++i)
#pragma unroll
            for (int j = 0; j < 4; ++j)
                acc[i][j] = __builtin_amdgcn_mfma_f32_16x16x32_bf16(af[i], bfv[j], acc[i][j], 0, 0, 0);
    }

    // epilogue: D[row=quad*4+r][col=lane&15] (m89/m91 layout)
#pragma unroll
    for (int i = 0; i < 4; ++i) {
        const int row = bm + wm + i * 16 + quad * 4;
#pragma unroll
        for (int j = 0; j < 4; ++j) {
            const int col = bn + wn + j * 16 + tr;
            OutT* op = O + (size_t)row * ldo + col;
#pragma unroll
            for (int r = 0; r < 4; ++r) {
                float v = acc[i][j][r];
                if (EPI == 1) v = silu_f(v);
                if (ATOMIC == 1) atomicAdd((float*)(op + (size_t)r * ldo), v);
                else             op[(size_t)r * ldo] = (OutT)v;
            }
        }
    }
}

// ---------------------------------------------------------------------------
// split-K partial reductions (plain-store split-K -> single buffer)
// ---------------------------------------------------------------------------
__global__ void reduce_sp(const float* __restrict__ SPp, float* __restrict__ SPb)
{
    const int i = (blockIdx.x * 256 + threadIdx.x) * 4;      // < 2048*128
    float4 a = *(const float4*)(SPp + i);
#pragma unroll
    for (int z = 1; z < 8; ++z) {
        const float4 b = *(const float4*)(SPp + (size_t)z * (BL_ * SPW) + i);
        a.x += b.x; a.y += b.y; a.z += b.z; a.w += b.w;
    }
    *(float4*)(SPb + i) = a;
}

__global__ void reduce_out(const float* __restrict__ OP, float* __restrict__ out)
{
    const int i = (blockIdx.x * 256 + threadIdx.x) * 4;      // < 2048*768
    float4 a = *(const float4*)(OP + i);
#pragma unroll
    for (int z = 1; z < 4; ++z) {
        const float4 b = *(const float4*)(OP + (size_t)z * (BL_ * H_) + i);
        a.x += b.x; a.y += b.y; a.z += b.z; a.w += b.w;
    }
    *(float4*)(out + i) = a;
}

// ---------------------------------------------------------------------------
// depthwise causal conv (K=4) + bias + silu over P0+P1 (split-K partials);
// writes bf16 HSb only (scans consume bf16)
// ---------------------------------------------------------------------------
__global__ void conv_kernel(const float* __restrict__ P0, const float* __restrict__ P1,
                            const float* __restrict__ cw, const float* __restrict__ cb,
                            __bf16* __restrict__ HSb)
{
    const int t = blockIdx.x * blockDim.x + threadIdx.x;
    const int d = t % DI_;
    const int bl = t / DI_;
    const int l = bl % L_;
    const float4 w = *(const float4*)(cw + (size_t)d * 4);
    const float wk[4] = {w.x, w.y, w.z, w.w};
    float acc = cb[d];
#pragma unroll
    for (int k = 0; k < 4; ++k) {
        const int ls = l - 3 + k;
        if (ls >= 0) {
            const size_t idx = (size_t)(bl - l + ls) * DI2_ + d;
            acc += wk[k] * (P0[idx] + P1[idx]);
        }
    }
    HSb[t] = (__bf16)silu_f(acc);
}

// ---------------------------------------------------------------------------
// dt[bl, d] = softplus(sum_r ts[bl, r] * dtwT[r, d] + dt_b[d])
// ---------------------------------------------------------------------------
__global__ void dt_kernel(const float* __restrict__ SP, const float* __restrict__ dtwT,
                          const float* __restrict__ dtb, float* __restrict__ DT)
{
    const int t = blockIdx.x * blockDim.x + threadIdx.x;
    const int d = t % DI_;
    const int bl = t / DI_;
    const float* ts = SP + (size_t)bl * SPW;
    float s = dtb[d];
#pragma unroll
    for (int r4 = 0; r4 < R_ / 4; ++r4) {
        const float4 tv = *(const float4*)(ts + r4 * 4);
        const float* wp = dtwT + (size_t)r4 * 4 * DI_ + d;
        s += tv.x * wp[0] + tv.y * wp[DI_] + tv.z * wp[2 * DI_] + tv.w * wp[3 * DI_];
    }
    DT[t] = (s > 20.f) ? s : log1pf(__expf(s));
}

// ---------------------------------------------------------------------------
// Chunked parallel scan, thread per (b,c,d), 16 n-states in registers.
// ---------------------------------------------------------------------------
__global__ __launch_bounds__(256) void scan_pass1(
    const float* __restrict__ DT, const __bf16* __restrict__ HSb,
    const float* __restrict__ SP, const float* __restrict__ A_log,
    float* __restrict__ Aprod, float* __restrict__ Bacc)
{
    const int t = blockIdx.x * blockDim.x + threadIdx.x;   // < B*C*DI
    const int d = t % DI_;
    const int y = t / DI_;
    const int c = y % C_;
    const int b = y / C_;
    float A[N_], s[N_], ap[N_];
    {
        const float4* alp = (const float4*)(A_log + (size_t)d * N_);
        const float4 a0 = alp[0], a1 = alp[1], a2 = alp[2], a3 = alp[3];
        const float av[N_] = {a0.x,a0.y,a0.z,a0.w, a1.x,a1.y,a1.z,a1.w,
                              a2.x,a2.y,a2.z,a2.w, a3.x,a3.y,a3.z,a3.w};
#pragma unroll
        for (int n = 0; n < N_; ++n) { A[n] = -__expf(av[n]); s[n] = 0.f; ap[n] = 1.f; }
    }
    for (int il = 0; il < CL_; ++il) {
        const size_t bl = (size_t)b * L_ + c * CL_ + il;
        const float dt = DT[bl * DI_ + d];
        const float hs = (float)HSb[bl * DI_ + d];
        const float4* Bp = (const float4*)(SP + bl * SPW + R_);
        const float4 b0 = Bp[0], b1 = Bp[1], b2 = Bp[2], b3 = Bp[3];
        const float Bv[N_] = {b0.x,b0.y,b0.z,b0.w, b1.x,b1.y,b1.z,b1.w,
                              b2.x,b2.y,b2.z,b2.w, b3.x,b3.y,b3.z,b3.w};
        const float dh = dt * hs;
#pragma unroll
        for (int n = 0; n < N_; ++n) {
            const float dA = __expf(dt * A[n]);
            s[n] = fmaf(dA, s[n], dh * Bv[n]);
            ap[n] *= dA;
        }
    }
    float4* Ap = (float4*)(Aprod + (size_t)t * N_);
    float4* Bc = (float4*)(Bacc  + (size_t)t * N_);
    Ap[0] = make_float4(ap[0], ap[1], ap[2], ap[3]);
    Ap[1] = make_float4(ap[4], ap[5], ap[6], ap[7]);
    Ap[2] = make_float4(ap[8], ap[9], ap[10], ap[11]);
    Ap[3] = make_float4(ap[12], ap[13], ap[14], ap[15]);
    Bc[0] = make_float4(s[0], s[1], s[2], s[3]);
    Bc[1] = make_float4(s[4], s[5], s[6], s[7]);
    Bc[2] = make_float4(s[8], s[9], s[10], s[11]);
    Bc[3] = make_float4(s[12], s[13], s[14], s[15]);
}

__global__ __launch_bounds__(256) void scan_pass2(
    const float* __restrict__ Aprod, const float* __restrict__ Bacc,
    float* __restrict__ Sinit)
{
    const int t = blockIdx.x * blockDim.x + threadIdx.x;    // < B*DI*N
    const int n = t & (N_ - 1);
    const int d = (t >> 4) % DI_;
    const int b = (t >> 4) / DI_;
    float s = 0.f;
    for (int c = 0; c < C_; ++c) {
        const size_t idx = (((size_t)b * C_ + c) * DI_ + d) * N_ + n;
        Sinit[idx] = s;
        s = fmaf(Aprod[idx], s, Bacc[idx]);
    }
}

__global__ __launch_bounds__(256) void scan_pass3(
    const float* __restrict__ DT, const __bf16* __restrict__ HSb,
    const float* __restrict__ SP, const float* __restrict__ P0,
    const float* __restrict__ P1, const float* __restrict__ A_log,
    const float* __restrict__ Dv, const float* __restrict__ Sinit,
    __bf16* __restrict__ Y)
{
    const int t = blockIdx.x * blockDim.x + threadIdx.x;   // < B*C*DI
    const int d = t % DI_;
    const int y = t / DI_;
    const int c = y % C_;
    const int b = y / C_;
    float A[N_], s[N_];
    {
        const float4* alp = (const float4*)(A_log + (size_t)d * N_);
        const float4 a0 = alp[0], a1 = alp[1], a2 = alp[2], a3 = alp[3];
        const float av[N_] = {a0.x,a0.y,a0.z,a0.w, a1.x,a1.y,a1.z,a1.w,
                              a2.x,a2.y,a2.z,a2.w, a3.x,a3.y,a3.z,a3.w};
#pragma unroll
        for (int n = 0; n < N_; ++n) A[n] = -__expf(av[n]);
    }
    {
        const float4* sp = (const float4*)(Sinit + (size_t)t * N_);
        const float4 s0 = sp[0], s1 = sp[1], s2 = sp[2], s3 = sp[3];
        s[0]=s0.x; s[1]=s0.y; s[2]=s0.z; s[3]=s0.w;
        s[4]=s1.x; s[5]=s1.y; s[6]=s1.z; s[7]=s1.w;
        s[8]=s2.x; s[9]=s2.y; s[10]=s2.z; s[11]=s2.w;
        s[12]=s3.x; s[13]=s3.y; s[14]=s3.z; s[15]=s3.w;
    }
    const float Dd = Dv[d];
    for (int il = 0; il < CL_; ++il) {
        const size_t bl = (size_t)b * L_ + c * CL_ + il;
        const float dt = DT[bl * DI_ + d];
        const float hs = (float)HSb[bl * DI_ + d];
        const float4* Bp = (const float4*)(SP + bl * SPW + R_);
        const float4 b0 = Bp[0], b1 = Bp[1], b2 = Bp[2], b3 = Bp[3];
        const float4 c0 = Bp[4], c1 = Bp[5], c2 = Bp[6], c3 = Bp[7];
        const float Bv[N_] = {b0.x,b0.y,b0.z,b0.w, b1.x,b1.y,b1.z,b1.w,
                              b2.x,b2.y,b2.z,b2.w, b3.x,b3.y,b3.z,b3.w};
        const float Cv[N_] = {c0.x,c0.y,c0.z,c0.w, c1.x,c1.y,c1.z,c1.w,
                              c2.x,c2.y,c2.z,c2.w, c3.x,c3.y,c3.z,c3.w};
        const float dh = dt * hs;
        float acc = 0.f;
#pragma unroll
        for (int n = 0; n < N_; ++n) {
            const float dA = __expf(dt * A[n]);
            s[n] = fmaf(dA, s[n], dh * Bv[n]);
            acc = fmaf(s[n], Cv[n], acc);
        }
        const size_t gidx = bl * DI2_ + DI_ + d;
        const float g = P0[gidx] + P1[gidx];
        Y[bl * DI_ + d] = (__bf16)((acc + hs * Dd) * silu_f(g));
    }
}

extern "C" void kernel_launch(void* const* d_in, const int* in_sizes, int n_in,
                              void* d_out, int out_size, void* d_ws, size_t ws_size,
                              hipStream_t stream) {
    const float* x        = (const float*)d_in[0];
    const float* w_up     = (const float*)d_in[1];
    const float* w_down   = (const float*)d_in[2];
    const float* conv_w   = (const float*)d_in[3];
    const float* conv_b   = (const float*)d_in[4];
    const float* x_proj_w = (const float*)d_in[5];
    const float* dt_w     = (const float*)d_in[6];
    const float* dt_b     = (const float*)d_in[7];
    const float* A_log    = (const float*)d_in[8];
    const float* Dvec     = (const float*)d_in[9];
    const float* w_oup    = (const float*)d_in[10];
    const float* w_odown  = (const float*)d_in[11];
    float* out = (float*)d_out;

    // ---- workspace layout, peak 176.2 MB (183+ proven safe) ----
    // phase A (prep1,G1): x_b[0,3.1) wup_b[3.1,22.0) | wdown_b[50.3,125.8) | U1b[125.8,176.2)
    // phase B (G2):       P0[0,25.2) P1[25.2,50.3)
    // phase C (post-G2):  wdown region -> {HSb,SPb,SPp,DTb,Yb,XPpad,dtwT,woup_b,wodown_b}
    //                     U1b region   -> {Aprod,Bacc,Sinit}; U2b over Aprod+Bacc after p2;
    //                     OP (G5 partials x4) over Sinit+spare after p3.
    char* base = (char*)d_ws;
    __bf16* x_b      = (__bf16*)base;                      //  3,145,728
    __bf16* wup_b    = (__bf16*)(base + 3145728);          // 18,874,368
    float*  P0       = (float*)base;                       // 25,165,824
    float*  P1       = (float*)(base + 25165824);          // 25,165,824
    char* r2 = base + 50331648;
    __bf16* wdown_b  = (__bf16*)r2;                        // 75,497,472
    __bf16* HSb      = (__bf16*)r2;                        //  6,291,456
    float*  SPb      = (float*)(r2 + 6291456);             //  1,048,576
    float*  SPp      = (float*)(r2 + 7340032);             //  8,388,608 (8 partials)
    float*  DTb      = (float*)(r2 + 15728640);            // 12,582,912
    __bf16* Yb       = (__bf16*)(r2 + 28311552);           //  6,291,456
    __bf16* XPpad    = (__bf16*)(r2 + 34603008);           //    393,216
    float*  dtwT     = (float*)(r2 + 34996224);            //    294,912
    __bf16* woup_b   = (__bf16*)(r2 + 35291136);           // 18,874,368
    __bf16* wodown_b = (__bf16*)(r2 + 54165504);           //  9,437,184 (ends 63.6M < 75.5M)
    char* r3 = r2 + 75497472;
    __bf16* U1b      = (__bf16*)r3;                        // 50,331,648
    __bf16* U2b      = (__bf16*)r3;                        // 25,165,824 (after p2)
    float*  Aprod    = (float*)r3;                         // 12,582,912
    float*  Bacc     = (float*)(r3 + 12582912);            // 12,582,912
    float*  Sinit    = (float*)(r3 + 25165824);            // 12,582,912
    float*  OP       = (float*)(r3 + 25165824);            // 25,165,824 (G5 partials, after p3)

    // fused prep: x, w_up, w_down -> bf16
    prep1<<<23808, 256, 0, stream>>>(x, w_up, w_down, x_b, wup_b, wdown_b);

    // G1: U1b = silu(x @ w_up^T)   [2048 x 12288], K=768
    gemm_bf16<1, 0, 0, __bf16><<<dim3(16, 96, 1), 256, 0, stream>>>(
        x_b, wup_b, U1b, BL_, DUP_, H_, H_, H_, DUP_);

    // G2: P = U1 @ w_down^T  [2048 x 3072], K=12288, split-K x2 plain-store
    // partials P0,P1; XCD-chunked tile swizzle for B-panel L2 reuse.
    gemm_bf16<0, 0, 1, float><<<dim3(16, 24, 2), 256, 0, stream>>>(
        U1b, wdown_b, P0, BL_, DI2_, DUP_ / 2, DUP_, DUP_, DI2_);

    // wdown_b dead from here: fused prep of small operands into r2
    prep2<<<7296, 256, 0, stream>>>(w_oup, w_odown, x_proj_w, dt_w,
                                    woup_b, wodown_b, XPpad, dtwT);

    // conv + silu over P0+P1 -> HSb bf16
    conv_kernel<<<(BL_ * DI_) / 256, 256, 0, stream>>>(P0, P1, conv_w, conv_b, HSb);

    // ssm projection: SP[2048][128] = HSb @ XPpad^T, split-K x8 plain-store + reduce
    gemm_bf16<0, 0, 0, float><<<dim3(16, 1, 8), 256, 0, stream>>>(
        HSb, XPpad, SPp, BL_, SPW, DI_ / 8, DI_, DI_, SPW);
    reduce_sp<<<(BL_ * SPW) / 1024, 256, 0, stream>>>(SPp, SPb);

    // dt -> DT
    dt_kernel<<<(BL_ * DI_) / 256, 256, 0, stream>>>(SPb, dtwT, dt_b, DTb);

    // chunked scan (C=64 chunks of 16)
    scan_pass1<<<(B_ * C_ * DI_) / 256, 256, 0, stream>>>(DTb, HSb, SPb, A_log, Aprod, Bacc);
    scan_pass2<<<(B_ * DI_ * N_) / 256, 256, 0, stream>>>(Aprod, Bacc, Sinit);
    scan_pass3<<<(B_ * C_ * DI_) / 256, 256, 0, stream>>>(
        DTb, HSb, SPb, P0, P1, A_log, Dvec, Sinit, Yb);

    // G4: U2b = silu(Y @ w_oup^T)   [2048 x 6144], K=1536
    gemm_bf16<1, 0, 0, __bf16><<<dim3(16, 48, 1), 256, 0, stream>>>(
        Yb, woup_b, U2b, BL_, DOUT_, DI_, DI_, DI_, DOUT_);

    // G5: out = U2 @ w_odown^T  [2048 x 768], K=6144, split-K x4 plain-store + reduce
    gemm_bf16<0, 0, 0, float><<<dim3(16, 6, 4), 256, 0, stream>>>(
        U2b, wodown_b, OP, BL_, H_, DOUT_ / 4, DOUT_, DOUT_, H_);
    reduce_out<<<(BL_ * H_) / 1024, 256, 0, stream>>>(OP, out);
}

// Round 5
// 786.192 us; speedup vs baseline: 1.1314x; 1.0441x over previous
//
#include <hip/hip_runtime.h>
#include <hip/hip_bf16.h>
#include <cstdint>

// ---- problem constants ----
#define B_   2
#define L_   1024
#define H_   768
#define DI_  1536
#define DI2_ 3072      // 2*DI
#define DUP_ 12288     // 2*DI*4
#define DOUT_ 6144     // 4*DI
#define N_   16
#define R_   48
#define SPW  128       // padded ssm_p row stride (R + 2N = 80 -> 128)
#define BL_  2048      // B*L
#define C_   64        // scan chunks
#define CL_  16        // L_/C_ steps per chunk

typedef __bf16 bf16x8 __attribute__((ext_vector_type(8)));
typedef float  f32x4  __attribute__((ext_vector_type(4)));
typedef unsigned int u32;

__device__ __forceinline__ float silu_f(float v) {
    return v / (1.f + __expf(-v));
}

__device__ __forceinline__ void async_ld16(const void* g, void* lds) {
    __builtin_amdgcn_global_load_lds(
        (const __attribute__((address_space(1))) u32*)g,
        (__attribute__((address_space(3))) u32*)lds, 16, 0, 0);
}

__device__ __forceinline__ void cvt8(const float* __restrict__ s, __bf16* __restrict__ d, int i)
{
    const float4 a = *(const float4*)(s + i);
    const float4 b = *(const float4*)(s + i + 4);
    bf16x8 v;
    v[0] = (__bf16)a.x; v[1] = (__bf16)a.y; v[2] = (__bf16)a.z; v[3] = (__bf16)a.w;
    v[4] = (__bf16)b.x; v[5] = (__bf16)b.y; v[6] = (__bf16)b.z; v[7] = (__bf16)b.w;
    *(bf16x8*)(d + i) = v;
}

// ---------------------------------------------------------------------------
// shared 128x128 MFMA GEMM tile body (m97 structure + XOR bank swizzle).
// NT: Out = A * W^T. BK=32, 256 threads, global_load_lds width-16 staging.
// ---------------------------------------------------------------------------
template<int EPI, int ATOMIC, typename OutT>
__device__ __forceinline__ void gemm_tile(
    const __bf16* __restrict__ A, const __bf16* __restrict__ W, OutT* __restrict__ O,
    int Kslice, int lda, int ldw, int ldo, int bm, int bn, int kbase)
{
    constexpr int BK = 32;
    __shared__ __bf16 As[128 * BK];
    __shared__ __bf16 Bs[128 * BK];

    const int tid  = threadIdx.x;
    const int wave = tid >> 6, lane = tid & 63;
    const int wm = (wave >> 1) * 64, wn = (wave & 1) * 64;
    const int quad = lane >> 4, tr = lane & 15;

    // staging: thread (srow, c) stores global k-chunk c^((srow>>1)&3) into slot c
    const int srow = tid >> 2;
    const int skc  = ((tid & 3) ^ ((srow >> 1) & 3)) * 8;
    const __bf16* Ag0 = A + (size_t)(bm + srow) * lda + kbase + skc;
    const __bf16* Ag1 = A + (size_t)(bm + srow + 64) * lda + kbase + skc;
    const __bf16* Wg0 = W + (size_t)(bn + srow) * ldw + kbase + skc;
    const __bf16* Wg1 = W + (size_t)(bn + srow + 64) * ldw + kbase + skc;
    __bf16* Al0 = &As[tid * 8];
    __bf16* Al1 = &As[2048 + tid * 8];
    __bf16* Bl0 = &Bs[tid * 8];
    __bf16* Bl1 = &Bs[2048 + tid * 8];

    // fragment read: row (wm|wn)+tr, want global chunk `quad` -> slot quad^((tr>>1)&3)
    const int fsw = (quad ^ ((tr >> 1) & 3)) * 8;
    const __bf16* arp = &As[(wm + tr) * BK + fsw];
    const __bf16* brp = &Bs[(wn + tr) * BK + fsw];

    f32x4 acc[4][4];
#pragma unroll
    for (int i = 0; i < 4; ++i)
#pragma unroll
        for (int j = 0; j < 4; ++j) acc[i][j] = (f32x4){0.f, 0.f, 0.f, 0.f};

    for (int k0 = 0; k0 < Kslice; k0 += BK) {
        __syncthreads();
        async_ld16(Ag0 + k0, Al0);
        async_ld16(Ag1 + k0, Al1);
        async_ld16(Wg0 + k0, Bl0);
        async_ld16(Wg1 + k0, Bl1);
        __syncthreads();

        bf16x8 af[4], bfv[4];
#pragma unroll
        for (int i = 0; i < 4; ++i) af[i]  = *(const bf16x8*)(arp + i * 16 * BK);
#pragma unroll
        for (int j = 0; j < 4; ++j) bfv[j] = *(const bf16x8*)(brp + j * 16 * BK);
#pragma unroll
        for (int i = 0; i < 4; ++i)
#pragma unroll
            for (int j = 0; j < 4; ++j)
                acc[i][j] = __builtin_amdgcn_mfma_f32_16x16x32_bf16(af[i], bfv[j], acc[i][j], 0, 0, 0);
    }

    // epilogue: D[row=quad*4+r][col=lane&15] (m89/m91 layout)
#pragma unroll
    for (int i = 0; i < 4; ++i) {
        const int row = bm + wm + i * 16 + quad * 4;
#pragma unroll
        for (int j = 0; j < 4; ++j) {
            const int col = bn + wn + j * 16 + tr;
            OutT* op = O + (size_t)row * ldo + col;
#pragma unroll
            for (int r = 0; r < 4; ++r) {
                float v = acc[i][j][r];
                if (EPI == 1) v = silu_f(v);
                if (ATOMIC == 1) atomicAdd((float*)(op + (size_t)r * ldo), v);
                else             op[(size_t)r * ldo] = (OutT)v;
            }
        }
    }
}

template<int EPI, int ATOMIC, typename OutT>
__global__ __launch_bounds__(256) void gemm_bf16(
    const __bf16* __restrict__ A, const __bf16* __restrict__ W, OutT* __restrict__ O,
    int M, int N, int Kslice, int lda, int ldw, int ldo)
{
    if (ATOMIC == 0) O += (size_t)blockIdx.z * (size_t)M * ldo;  // partial buffer
    gemm_tile<EPI, ATOMIC, OutT>(A, W, O, Kslice, lda, ldw, ldo,
                                 blockIdx.x * 128, blockIdx.y * 128,
                                 blockIdx.z * Kslice);
}

// ---------------------------------------------------------------------------
// prep1: fused fp32->bf16 conversions needed before G1.
// segs: x (768 blk), w_up (4608); 256 thr x 8 elems each.
// ---------------------------------------------------------------------------
__global__ void prep1(const float* __restrict__ x, const float* __restrict__ wup,
                      __bf16* __restrict__ xb, __bf16* __restrict__ wupb)
{
    const int bid = blockIdx.x;
    if (bid < 768) cvt8(x,   xb,   (bid * 256 + threadIdx.x) * 8);
    else           cvt8(wup, wupb, ((bid - 768) * 256 + threadIdx.x) * 8);
}

// ---------------------------------------------------------------------------
// g1_fused: G1 GEMM tiles (blocks 0..1535) + w_down fp32->bf16 conversion
// (blocks 1536..19967). Both depend only on prep1-stage data; the cvt blocks
// drain into CU idle tails of the GEMM instead of serializing as a second
// dispatch (w_down is 151 MB fp32 -> ~35 us of pure conversion).
// ---------------------------------------------------------------------------
__global__ __launch_bounds__(256) void g1_fused(
    const __bf16* __restrict__ xb, const __bf16* __restrict__ wupb,
    __bf16* __restrict__ U1b,
    const float* __restrict__ wdn, __bf16* __restrict__ wdnb)
{
    const int bid = blockIdx.x;
    if (bid < 1536) {
        const int bx = bid & 15, by = bid >> 4;
        gemm_tile<1, 0, __bf16>(xb, wupb, U1b, H_, H_, H_, DUP_,
                                bx * 128, by * 128, 0);
    } else {
        cvt8(wdn, wdnb, ((bid - 1536) * 256 + threadIdx.x) * 8);
    }
}

// ---------------------------------------------------------------------------
// conv_prep2: depthwise causal conv (K=4)+bias+silu over P0+P1 (blocks
// 0..12287) + post-G2 prep (w_oup cvt 4608, w_odown cvt 2304, pad_xp 96,
// transpose_dtw 288). All depend only on G2 / kernel inputs.
// ---------------------------------------------------------------------------
__global__ void conv_prep2(const float* __restrict__ P0, const float* __restrict__ P1,
                           const float* __restrict__ cw, const float* __restrict__ cb,
                           __bf16* __restrict__ HSb,
                           const float* __restrict__ woup, const float* __restrict__ wodn,
                           const float* __restrict__ xp, const float* __restrict__ dtw,
                           __bf16* __restrict__ woupb, __bf16* __restrict__ wodnb,
                           __bf16* __restrict__ xppad, float* __restrict__ dtwT)
{
    const int bid = blockIdx.x;
    if (bid < 12288) {
        const int t = bid * 256 + threadIdx.x;
        const int d = t % DI_;
        const int bl = t / DI_;
        const int l = bl % L_;
        const float4 w = *(const float4*)(cw + (size_t)d * 4);
        const float wk[4] = {w.x, w.y, w.z, w.w};
        float acc = cb[d];
#pragma unroll
        for (int k = 0; k < 4; ++k) {
            const int ls = l - 3 + k;
            if (ls >= 0) {
                const size_t idx = (size_t)(bl - l + ls) * DI2_ + d;
                acc += wk[k] * (P0[idx] + P1[idx]);
            }
        }
        HSb[t] = (__bf16)silu_f(acc);
        return;
    }
    const int pid = bid - 12288;
    if (pid < 4608)        cvt8(woup, woupb, (pid * 256 + threadIdx.x) * 8);
    else if (pid < 6912)   cvt8(wodn, wodnb, ((pid - 4608) * 256 + threadIdx.x) * 8);
    else if (pid < 7008) {
        const int i = ((pid - 6912) * 256 + threadIdx.x) * 8;   // < 128*1536
        const int j = i / DI_;
        bf16x8 v;
        if (j < 80) {
            const float4 a = *(const float4*)(xp + i);
            const float4 b = *(const float4*)(xp + i + 4);
            v[0] = (__bf16)a.x; v[1] = (__bf16)a.y; v[2] = (__bf16)a.z; v[3] = (__bf16)a.w;
            v[4] = (__bf16)b.x; v[5] = (__bf16)b.y; v[6] = (__bf16)b.z; v[7] = (__bf16)b.w;
        } else {
            for (int k = 0; k < 8; ++k) v[k] = (__bf16)0.f;
        }
        *(bf16x8*)(xppad + i) = v;
    } else {
        const int i = (pid - 7008) * 256 + threadIdx.x;         // < 48*1536
        const int r = i / DI_, d = i % DI_;
        dtwT[i] = dtw[(size_t)d * R_ + r];
    }
}

// ---------------------------------------------------------------------------
// split-K partial reductions (plain-store split-K -> single buffer)
// ---------------------------------------------------------------------------
__global__ void reduce_sp(const float* __restrict__ SPp, float* __restrict__ SPb)
{
    const int i = (blockIdx.x * 256 + threadIdx.x) * 4;      // < 2048*128
    float4 a = *(const float4*)(SPp + i);
#pragma unroll
    for (int z = 1; z < 8; ++z) {
        const float4 b = *(const float4*)(SPp + (size_t)z * (BL_ * SPW) + i);
        a.x += b.x; a.y += b.y; a.z += b.z; a.w += b.w;
    }
    *(float4*)(SPb + i) = a;
}

__global__ void reduce_out(const float* __restrict__ OP, float* __restrict__ out)
{
    const int i = (blockIdx.x * 256 + threadIdx.x) * 4;      // < 2048*768
    float4 a = *(const float4*)(OP + i);
#pragma unroll
    for (int z = 1; z < 8; ++z) {
        const float4 b = *(const float4*)(OP + (size_t)z * (BL_ * H_) + i);
        a.x += b.x; a.y += b.y; a.z += b.z; a.w += b.w;
    }
    *(float4*)(out + i) = a;
}

// ---------------------------------------------------------------------------
// dt[bl, d] = softplus(sum_r ts[bl, r] * dtwT[r, d] + dt_b[d])
// ---------------------------------------------------------------------------
__global__ void dt_kernel(const float* __restrict__ SP, const float* __restrict__ dtwT,
                          const float* __restrict__ dtb, float* __restrict__ DT)
{
    const int t = blockIdx.x * blockDim.x + threadIdx.x;
    const int d = t % DI_;
    const int bl = t / DI_;
    const float* ts = SP + (size_t)bl * SPW;
    float s = dtb[d];
#pragma unroll
    for (int r4 = 0; r4 < R_ / 4; ++r4) {
        const float4 tv = *(const float4*)(ts + r4 * 4);
        const float* wp = dtwT + (size_t)r4 * 4 * DI_ + d;
        s += tv.x * wp[0] + tv.y * wp[DI_] + tv.z * wp[2 * DI_] + tv.w * wp[3 * DI_];
    }
    DT[t] = (s > 20.f) ? s : log1pf(__expf(s));
}

// ---------------------------------------------------------------------------
// Chunked parallel scan, thread per (b,c,d), 16 n-states in registers.
// ---------------------------------------------------------------------------
__global__ __launch_bounds__(256) void scan_pass1(
    const float* __restrict__ DT, const __bf16* __restrict__ HSb,
    const float* __restrict__ SP, const float* __restrict__ A_log,
    float* __restrict__ Aprod, float* __restrict__ Bacc)
{
    const int t = blockIdx.x * blockDim.x + threadIdx.x;   // < B*C*DI
    const int d = t % DI_;
    const int y = t / DI_;
    const int c = y % C_;
    const int b = y / C_;
    float A[N_], s[N_], ap[N_];
    {
        const float4* alp = (const float4*)(A_log + (size_t)d * N_);
        const float4 a0 = alp[0], a1 = alp[1], a2 = alp[2], a3 = alp[3];
        const float av[N_] = {a0.x,a0.y,a0.z,a0.w, a1.x,a1.y,a1.z,a1.w,
                              a2.x,a2.y,a2.z,a2.w, a3.x,a3.y,a3.z,a3.w};
#pragma unroll
        for (int n = 0; n < N_; ++n) { A[n] = -__expf(av[n]); s[n] = 0.f; ap[n] = 1.f; }
    }
    for (int il = 0; il < CL_; ++il) {
        const size_t bl = (size_t)b * L_ + c * CL_ + il;
        const float dt = DT[bl * DI_ + d];
        const float hs = (float)HSb[bl * DI_ + d];
        const float4* Bp = (const float4*)(SP + bl * SPW + R_);
        const float4 b0 = Bp[0], b1 = Bp[1], b2 = Bp[2], b3 = Bp[3];
        const float Bv[N_] = {b0.x,b0.y,b0.z,b0.w, b1.x,b1.y,b1.z,b1.w,
                              b2.x,b2.y,b2.z,b2.w, b3.x,b3.y,b3.z,b3.w};
        const float dh = dt * hs;
#pragma unroll
        for (int n = 0; n < N_; ++n) {
            const float dA = __expf(dt * A[n]);
            s[n] = fmaf(dA, s[n], dh * Bv[n]);
            ap[n] *= dA;
        }
    }
    float4* Ap = (float4*)(Aprod + (size_t)t * N_);
    float4* Bc = (float4*)(Bacc  + (size_t)t * N_);
    Ap[0] = make_float4(ap[0], ap[1], ap[2], ap[3]);
    Ap[1] = make_float4(ap[4], ap[5], ap[6], ap[7]);
    Ap[2] = make_float4(ap[8], ap[9], ap[10], ap[11]);
    Ap[3] = make_float4(ap[12], ap[13], ap[14], ap[15]);
    Bc[0] = make_float4(s[0], s[1], s[2], s[3]);
    Bc[1] = make_float4(s[4], s[5], s[6], s[7]);
    Bc[2] = make_float4(s[8], s[9], s[10], s[11]);
    Bc[3] = make_float4(s[12], s[13], s[14], s[15]);
}

__global__ __launch_bounds__(256) void scan_pass2(
    const float* __restrict__ Aprod, const float* __restrict__ Bacc,
    float* __restrict__ Sinit)
{
    const int t = blockIdx.x * blockDim.x + threadIdx.x;    // < B*DI*N
    const int n = t & (N_ - 1);
    const int d = (t >> 4) % DI_;
    const int b = (t >> 4) / DI_;
    float s = 0.f;
    for (int c = 0; c < C_; ++c) {
        const size_t idx = (((size_t)b * C_ + c) * DI_ + d) * N_ + n;
        Sinit[idx] = s;
        s = fmaf(Aprod[idx], s, Bacc[idx]);
    }
}

__global__ __launch_bounds__(256) void scan_pass3(
    const float* __restrict__ DT, const __bf16* __restrict__ HSb,
    const float* __restrict__ SP, const float* __restrict__ P0,
    const float* __restrict__ P1, const float* __restrict__ A_log,
    const float* __restrict__ Dv, const float* __restrict__ Sinit,
    __bf16* __restrict__ Y)
{
    const int t = blockIdx.x * blockDim.x + threadIdx.x;   // < B*C*DI
    const int d = t % DI_;
    const int y = t / DI_;
    const int c = y % C_;
    const int b = y / C_;
    float A[N_], s[N_];
    {
        const float4* alp = (const float4*)(A_log + (size_t)d * N_);
        const float4 a0 = alp[0], a1 = alp[1], a2 = alp[2], a3 = alp[3];
        const float av[N_] = {a0.x,a0.y,a0.z,a0.w, a1.x,a1.y,a1.z,a1.w,
                              a2.x,a2.y,a2.z,a2.w, a3.x,a3.y,a3.z,a3.w};
#pragma unroll
        for (int n = 0; n < N_; ++n) A[n] = -__expf(av[n]);
    }
    {
        const float4* sp = (const float4*)(Sinit + (size_t)t * N_);
        const float4 s0 = sp[0], s1 = sp[1], s2 = sp[2], s3 = sp[3];
        s[0]=s0.x; s[1]=s0.y; s[2]=s0.z; s[3]=s0.w;
        s[4]=s1.x; s[5]=s1.y; s[6]=s1.z; s[7]=s1.w;
        s[8]=s2.x; s[9]=s2.y; s[10]=s2.z; s[11]=s2.w;
        s[12]=s3.x; s[13]=s3.y; s[14]=s3.z; s[15]=s3.w;
    }
    const float Dd = Dv[d];
    for (int il = 0; il < CL_; ++il) {
        const size_t bl = (size_t)b * L_ + c * CL_ + il;
        const float dt = DT[bl * DI_ + d];
        const float hs = (float)HSb[bl * DI_ + d];
        const float4* Bp = (const float4*)(SP + bl * SPW + R_);
        const float4 b0 = Bp[0], b1 = Bp[1], b2 = Bp[2], b3 = Bp[3];
        const float4 c0 = Bp[4], c1 = Bp[5], c2 = Bp[6], c3 = Bp[7];
        const float Bv[N_] = {b0.x,b0.y,b0.z,b0.w, b1.x,b1.y,b1.z,b1.w,
                              b2.x,b2.y,b2.z,b2.w, b3.x,b3.y,b3.z,b3.w};
        const float Cv[N_] = {c0.x,c0.y,c0.z,c0.w, c1.x,c1.y,c1.z,c1.w,
                              c2.x,c2.y,c2.z,c2.w, c3.x,c3.y,c3.z,c3.w};
        const float dh = dt * hs;
        float acc = 0.f;
#pragma unroll
        for (int n = 0; n < N_; ++n) {
            const float dA = __expf(dt * A[n]);
            s[n] = fmaf(dA, s[n], dh * Bv[n]);
            acc = fmaf(s[n], Cv[n], acc);
        }
        const size_t gidx = bl * DI2_ + DI_ + d;
        const float g = P0[gidx] + P1[gidx];
        Y[bl * DI_ + d] = (__bf16)((acc + hs * Dd) * silu_f(g));
    }
}

extern "C" void kernel_launch(void* const* d_in, const int* in_sizes, int n_in,
                              void* d_out, int out_size, void* d_ws, size_t ws_size,
                              hipStream_t stream) {
    const float* x        = (const float*)d_in[0];
    const float* w_up     = (const float*)d_in[1];
    const float* w_down   = (const float*)d_in[2];
    const float* conv_w   = (const float*)d_in[3];
    const float* conv_b   = (const float*)d_in[4];
    const float* x_proj_w = (const float*)d_in[5];
    const float* dt_w     = (const float*)d_in[6];
    const float* dt_b     = (const float*)d_in[7];
    const float* A_log    = (const float*)d_in[8];
    const float* Dvec     = (const float*)d_in[9];
    const float* w_oup    = (const float*)d_in[10];
    const float* w_odown  = (const float*)d_in[11];
    float* out = (float*)d_out;

    // ---- workspace layout, peak 176.2 MB (183+ proven safe) ----
    // phase A (prep1,G1): x_b[0,3.1) wup_b[3.1,22.0) | wdown_b[50.3,125.8) | U1b[125.8,176.2)
    // phase B (G2):       P0[0,25.2) P1[25.2,50.3)
    // phase C (post-G2):  wdown region -> {HSb,SPb,SPp,DTb,Yb,XPpad,dtwT,woup_b,wodown_b}
    //                     U1b region   -> {Aprod,Bacc,Sinit}; U2b over Aprod+Bacc after p2;
    //                     OP (G5 partials x8) over dead P0/P1 after p3.
    char* base = (char*)d_ws;
    __bf16* x_b      = (__bf16*)base;                      //  3,145,728
    __bf16* wup_b    = (__bf16*)(base + 3145728);          // 18,874,368
    float*  P0       = (float*)base;                       // 25,165,824
    float*  P1       = (float*)(base + 25165824);          // 25,165,824
    float*  OP       = (float*)base;                       // 50,331,648 (G5 partials, after p3)
    char* r2 = base + 50331648;
    __bf16* wdown_b  = (__bf16*)r2;                        // 75,497,472
    __bf16* HSb      = (__bf16*)r2;                        //  6,291,456
    float*  SPb      = (float*)(r2 + 6291456);             //  1,048,576
    float*  SPp      = (float*)(r2 + 7340032);             //  8,388,608 (8 partials)
    float*  DTb      = (float*)(r2 + 15728640);            // 12,582,912
    __bf16* Yb       = (__bf16*)(r2 + 28311552);           //  6,291,456
    __bf16* XPpad    = (__bf16*)(r2 + 34603008);           //    393,216
    float*  dtwT     = (float*)(r2 + 34996224);            //    294,912
    __bf16* woup_b   = (__bf16*)(r2 + 35291136);           // 18,874,368
    __bf16* wodown_b = (__bf16*)(r2 + 54165504);           //  9,437,184 (ends 63.6M < 75.5M)
    char* r3 = r2 + 75497472;
    __bf16* U1b      = (__bf16*)r3;                        // 50,331,648
    __bf16* U2b      = (__bf16*)r3;                        // 25,165,824 (after p2)
    float*  Aprod    = (float*)r3;                         // 12,582,912
    float*  Bacc     = (float*)(r3 + 12582912);            // 12,582,912
    float*  Sinit    = (float*)(r3 + 25165824);            // 12,582,912

    // prep: x, w_up -> bf16
    prep1<<<5376, 256, 0, stream>>>(x, w_up, x_b, wup_b);

    // G1 (1536 tile blocks) + w_down cvt (18432 blocks) in ONE launch:
    // U1b = silu(x @ w_up^T) [2048 x 12288] K=768; wdown_b = bf16(w_down)
    g1_fused<<<19968, 256, 0, stream>>>(x_b, wup_b, U1b, w_down, wdown_b);

    // G2: P = U1 @ w_down^T  [2048 x 3072], K=12288, split-K x2 plain-store
    // partials P0,P1 (no swizzle -- round-4 A/B showed swizzle hurts here)
    gemm_bf16<0, 0, float><<<dim3(16, 24, 2), 256, 0, stream>>>(
        U1b, wdown_b, P0, BL_, DI2_, DUP_ / 2, DUP_, DUP_, DI2_);

    // conv+silu over P0+P1 -> HSb (12288 blocks) + post-G2 prep (7296 blocks)
    conv_prep2<<<19584, 256, 0, stream>>>(P0, P1, conv_w, conv_b, HSb,
                                          w_oup, w_odown, x_proj_w, dt_w,
                                          woup_b, wodown_b, XPpad, dtwT);

    // ssm projection: SP[2048][128] = HSb @ XPpad^T, split-K x8 plain-store + reduce
    gemm_bf16<0, 0, float><<<dim3(16, 1, 8), 256, 0, stream>>>(
        HSb, XPpad, SPp, BL_, SPW, DI_ / 8, DI_, DI_, SPW);
    reduce_sp<<<(BL_ * SPW) / 1024, 256, 0, stream>>>(SPp, SPb);

    // dt -> DT
    dt_kernel<<<(BL_ * DI_) / 256, 256, 0, stream>>>(SPb, dtwT, dt_b, DTb);

    // chunked scan (C=64 chunks of 16)
    scan_pass1<<<(B_ * C_ * DI_) / 256, 256, 0, stream>>>(DTb, HSb, SPb, A_log, Aprod, Bacc);
    scan_pass2<<<(B_ * DI_ * N_) / 256, 256, 0, stream>>>(Aprod, Bacc, Sinit);
    scan_pass3<<<(B_ * C_ * DI_) / 256, 256, 0, stream>>>(
        DTb, HSb, SPb, P0, P1, A_log, Dvec, Sinit, Yb);

    // G4: U2b = silu(Y @ w_oup^T)   [2048 x 6144], K=1536
    gemm_bf16<1, 0, __bf16><<<dim3(16, 48, 1), 256, 0, stream>>>(
        Yb, woup_b, U2b, BL_, DOUT_, DI_, DI_, DI_, DOUT_);

    // G5: out = U2 @ w_odown^T  [2048 x 768], K=6144, split-K x8 plain-store
    // into dead P region (768 blocks = 3/CU vs 384 = half-idle 2nd round)
    gemm_bf16<0, 0, float><<<dim3(16, 6, 8), 256, 0, stream>>>(
        U2b, wodown_b, OP, BL_, H_, DOUT_ / 8, DOUT_, DOUT_, H_);
    reduce_out<<<(BL_ * H_) / 1024, 256, 0, stream>>>(OP, out);
}